// Round 4
// baseline (804.345 us; speedup 1.0000x reference)
//
#include <hip/hip_runtime.h>
#include <cstdint>

// Net_79139067396690: MC-dropout moment-propagation MLP, MFMA version.
//   h   = relu(0.5*x@W1^T + 0.5*sqrt((x^2)@(W1^2)^T) * eps1/sqrt(1000))
//   out =      0.5*h@W2^T + 0.5*sqrt((h^2)@(W2^2)^T) * eps2/sqrt(1000)
// GEMM1 on bf16 matrix cores (16x16x32), layer 2 + RNG on VALU.
// eps = jax.random.normal, partitionable threefry (verified round 2).
// Round 4: kill scratch spills (drop B-prefetch regs; live set < 256 unified),
//          vectorize layer-2 hbuf reads (short8, stride 264).

#define K_DIM 784
#define KP 800                 // K padded to multiple of 32 in the W1 pack
#define N_HID 256
#define N_OUT 10
#define BM 128
#define NSTEP 25               // KP/32
#define WSQ_OFF (N_HID * KP)   // ushort offset of squared-W pack
#define HSTRIDE 264            // u16 stride of hbuf rows (16B-aligned, bank-safe)

using short8 = __attribute__((ext_vector_type(8))) short;
using floatx4 = __attribute__((ext_vector_type(4))) float;
typedef uint16_t u16;

// ---- Threefry-2x32 (JAX-compatible) ----
__host__ __device__ inline void threefry2x32(uint32_t k0, uint32_t k1,
                                             uint32_t x0, uint32_t x1,
                                             uint32_t& o0, uint32_t& o1) {
  uint32_t ks[3] = {k0, k1, k0 ^ k1 ^ 0x1BD11BDAu};
  x0 += ks[0];
  x1 += ks[1];
  const uint32_t rot[8] = {13u, 15u, 26u, 6u, 17u, 29u, 16u, 24u};
#pragma unroll
  for (int i = 0; i < 5; ++i) {
#pragma unroll
    for (int j = 0; j < 4; ++j) {
      uint32_t r = rot[(i & 1) * 4 + j];
      x0 += x1;
      x1 = (x1 << r) | (x1 >> (32u - r));
      x1 ^= x0;
    }
    x0 += ks[(i + 1) % 3];
    x1 += ks[(i + 2) % 3] + (uint32_t)(i + 1);
  }
  o0 = x0;
  o1 = x1;
}

// bits -> N(0,1), matching jax.random.normal (mantissa-uniform + Giles erfinv)
__device__ __forceinline__ float bits_to_normal(uint32_t bits) {
  const float lo = -0.99999994f;  // nextafterf(-1,0)
  float u01 = __uint_as_float((bits >> 9) | 0x3F800000u) - 1.0f;
  float u = fmaxf(lo, u01 * 2.0f + lo);
  float w = -log1pf(-u * u);
  float p;
  if (w < 5.0f) {
    w -= 2.5f;
    p = 2.81022636e-08f;
    p = fmaf(p, w, 3.43273939e-07f);
    p = fmaf(p, w, -3.5233877e-06f);
    p = fmaf(p, w, -4.39150654e-06f);
    p = fmaf(p, w, 0.00021858087f);
    p = fmaf(p, w, -0.00125372503f);
    p = fmaf(p, w, -0.00417768164f);
    p = fmaf(p, w, 0.246640727f);
    p = fmaf(p, w, 1.50140941f);
  } else {
    w = sqrtf(w) - 3.0f;
    p = -0.000200214257f;
    p = fmaf(p, w, 0.000100950558f);
    p = fmaf(p, w, 0.00134934322f);
    p = fmaf(p, w, -0.00367342844f);
    p = fmaf(p, w, 0.00573950773f);
    p = fmaf(p, w, -0.0076224613f);
    p = fmaf(p, w, 0.00943887047f);
    p = fmaf(p, w, 1.00167406f);
    p = fmaf(p, w, 2.83297682f);
  }
  return 1.41421356f * (p * u);
}

__device__ __forceinline__ float eps_part(uint32_t ka, uint32_t kb, uint32_t i) {
  uint32_t o0, o1;
  threefry2x32(ka, kb, 0u, i, o0, o1);
  return bits_to_normal(o0 ^ o1);
}

// f32 -> bf16 round-to-nearest-even
__host__ __device__ __forceinline__ u16 f2bf(float f) {
  uint32_t u;
#ifdef __HIP_DEVICE_COMPILE__
  u = __float_as_uint(f);
#else
  __builtin_memcpy(&u, &f, 4);
#endif
  return (u16)((u + 0x7FFFu + ((u >> 16) & 1u)) >> 16);
}

__device__ __forceinline__ float bf2f(u16 b) {
  return __uint_as_float((uint32_t)b << 16);
}

// ---- pre-pack W1 -> bf16 {w, w^2}, K padded to 800 with zeros ----
__global__ __launch_bounds__(256) void pack_w1(const float* __restrict__ W1,
                                               u16* __restrict__ bp) {
  const int col = blockIdx.x;  // 0..255
  for (int k = threadIdx.x; k < KP; k += 256) {
    float w = (k < K_DIM) ? W1[col * K_DIM + k] : 0.0f;
    bp[col * KP + k] = f2bf(w);
    bp[WSQ_OFF + col * KP + k] = f2bf(w * w);
  }
}

// ---- fused main kernel: one block = 128 batch rows, full N=256 ----
__global__ __launch_bounds__(512, 2) void fused_mfma(
    const float* __restrict__ x, const u16* __restrict__ bp,
    const float* __restrict__ W2, float* __restrict__ out,
    uint32_t k1a, uint32_t k1b, uint32_t k2a, uint32_t k2b) {
  __shared__ u16 sA[2][2][BM * 32];    // [dbuf][tensor: x, x^2][swizzled row*32+k]
  __shared__ u16 hbuf[BM * HSTRIDE];   // h (bf16)
  __shared__ float sW2[10 * 260];

  const int tid = threadIdx.x;
  const int lane = tid & 63;
  const int l15 = lane & 15;
  const int lhal = lane >> 4;  // 0..3
  const int wid = tid >> 6;    // 0..7
  const int wm = wid >> 2;     // 0..1  (m-direction)
  const int wn = wid & 3;      // 0..3  (n-direction)
  const int gr0 = blockIdx.x * BM;

  // --- staging geometry: thread -> (row, 8-wide k chunk) of the A tile ---
  const int srow = tid >> 2;         // 0..127
  const int skq = (tid & 3) * 8;     // 0,8,16,24
  const float* xptr = x + (size_t)(gr0 + srow) * K_DIM + skq;
  const int sidx = (srow * 32 + skq) ^ ((srow & 7) << 3);  // XOR swizzle (u16 units)

  // --- per-wave B offsets into the bf16 pack (u16 units, 32-bit) ---
  uint32_t boff[4];
#pragma unroll
  for (int j = 0; j < 4; ++j) {
    int col = wn * 64 + j * 16 + l15;
    boff[j] = (uint32_t)col * KP + (uint32_t)lhal * 8;
  }

  // --- per-wave A fragment LDS indices ---
  int aidx[4];
#pragma unroll
  for (int i = 0; i < 4; ++i) {
    int r = wm * 64 + i * 16 + l15;
    aidx[i] = (r * 32 + lhal * 8) ^ ((r & 7) << 3);
  }

  floatx4 accm[4][4], accv[4][4];
#pragma unroll
  for (int i = 0; i < 4; ++i)
#pragma unroll
    for (int j = 0; j < 4; ++j)
#pragma unroll
      for (int g = 0; g < 4; ++g) { accm[i][j][g] = 0.0f; accv[i][j][g] = 0.0f; }

  float4 q0, q1;
  auto loadX = [&](int kk) {
    if (kk + skq + 8 <= K_DIM) {  // K tail (784 = 24*32+16): zero-fill OOB chunks
      q0 = *reinterpret_cast<const float4*>(xptr + kk);
      q1 = *reinterpret_cast<const float4*>(xptr + kk + 4);
    } else {
      q0 = make_float4(0.f, 0.f, 0.f, 0.f);
      q1 = make_float4(0.f, 0.f, 0.f, 0.f);
    }
  };
  auto writeA = [&](int buf) {
    short8 va, v2;
    va[0] = (short)f2bf(q0.x); v2[0] = (short)f2bf(q0.x * q0.x);
    va[1] = (short)f2bf(q0.y); v2[1] = (short)f2bf(q0.y * q0.y);
    va[2] = (short)f2bf(q0.z); v2[2] = (short)f2bf(q0.z * q0.z);
    va[3] = (short)f2bf(q0.w); v2[3] = (short)f2bf(q0.w * q0.w);
    va[4] = (short)f2bf(q1.x); v2[4] = (short)f2bf(q1.x * q1.x);
    va[5] = (short)f2bf(q1.y); v2[5] = (short)f2bf(q1.y * q1.y);
    va[6] = (short)f2bf(q1.z); v2[6] = (short)f2bf(q1.z * q1.z);
    va[7] = (short)f2bf(q1.w); v2[7] = (short)f2bf(q1.w * q1.w);
    *reinterpret_cast<short8*>(&sA[buf][0][sidx]) = va;
    *reinterpret_cast<short8*>(&sA[buf][1][sidx]) = v2;
  };

  // prologue: stage step 0
  loadX(0);
  writeA(0);
  __syncthreads();

  for (int s = 0; s < NSTEP; ++s) {
    const int cur = s & 1, nxt = cur ^ 1;
    const bool have = (s + 1 < NSTEP);
    const int kk = s * 32;
    // B for this step, fresh from L2 (no prefetch regs — keeps us under 256)
    short8 bmc[4], bvc[4];
#pragma unroll
    for (int j = 0; j < 4; ++j) {
      bmc[j] = *reinterpret_cast<const short8*>(&bp[boff[j] + kk]);
      bvc[j] = *reinterpret_cast<const short8*>(&bp[WSQ_OFF + boff[j] + kk]);
    }
    if (have) loadX(kk + 32);  // x prefetch (8 regs in flight)
    short8 af[4], avf[4];
#pragma unroll
    for (int i = 0; i < 4; ++i) {
      af[i] = *reinterpret_cast<const short8*>(&sA[cur][0][aidx[i]]);
      avf[i] = *reinterpret_cast<const short8*>(&sA[cur][1][aidx[i]]);
    }
#pragma unroll
    for (int i = 0; i < 4; ++i)
#pragma unroll
      for (int j = 0; j < 4; ++j) {
        accm[i][j] = __builtin_amdgcn_mfma_f32_16x16x32_bf16(af[i], bmc[j], accm[i][j], 0, 0, 0);
        accv[i][j] = __builtin_amdgcn_mfma_f32_16x16x32_bf16(avf[i], bvc[j], accv[i][j], 0, 0, 0);
      }
    if (have) writeA(nxt);  // convert + ds_write for next step
    __syncthreads();
  }

  // --- stage W2 (f32) ---
#pragma unroll
  for (int g = 0; g < 5; ++g) {
    int gg = tid + g * 512;  // 2560 = 5*512 exactly
    sW2[(gg >> 8) * 260 + (gg & 255)] = W2[gg];
  }

  // --- layer-1 epilogue: eps1 + relu -> hbuf (bf16) ---
  const float INV = 0.031622776601683794f;  // 1/sqrt(1000)
#pragma unroll
  for (int i = 0; i < 4; ++i)
#pragma unroll
    for (int j = 0; j < 4; ++j)
#pragma unroll
      for (int g = 0; g < 4; ++g) {
        int rl = wm * 64 + i * 16 + lhal * 4 + g;  // C/D: row=(lane>>4)*4+reg
        int c = wn * 64 + j * 16 + l15;            //      col=lane&15
        float mean = 0.5f * accm[i][j][g];
        float sd = 0.5f * sqrtf(accv[i][j][g]);
        uint32_t idx = (uint32_t)(gr0 + rl) * 256u + (uint32_t)c;
        float eps = eps_part(k1a, k1b, idx);
        float h = fmaxf(mean + sd * (eps * INV), 0.0f);
        hbuf[rl * HSTRIDE + c] = f2bf(h);
      }
  __syncthreads();

  // --- layer 2 (VALU): 128x10 outputs, K=256 from hbuf, short8-vectorized ---
#pragma unroll
  for (int it = 0; it < 3; ++it) {
    int item = tid + it * 512;
    if (item < BM * N_OUT) {
      int rl = item / N_OUT;
      int c = item - rl * N_OUT;
      float m = 0.0f, v = 0.0f;
#pragma unroll 4
      for (int k8 = 0; k8 < N_HID / 8; ++k8) {
        short8 hv = *reinterpret_cast<const short8*>(&hbuf[rl * HSTRIDE + k8 * 8]);
        const float4 w0 = *reinterpret_cast<const float4*>(&sW2[c * 260 + k8 * 8]);
        const float4 w1 = *reinterpret_cast<const float4*>(&sW2[c * 260 + k8 * 8 + 4]);
        float h0 = bf2f((u16)hv[0]), h1 = bf2f((u16)hv[1]);
        float h2 = bf2f((u16)hv[2]), h3 = bf2f((u16)hv[3]);
        float h4 = bf2f((u16)hv[4]), h5 = bf2f((u16)hv[5]);
        float h6 = bf2f((u16)hv[6]), h7 = bf2f((u16)hv[7]);
        m = fmaf(h0, w0.x, m); v = fmaf(h0 * h0, w0.x * w0.x, v);
        m = fmaf(h1, w0.y, m); v = fmaf(h1 * h1, w0.y * w0.y, v);
        m = fmaf(h2, w0.z, m); v = fmaf(h2 * h2, w0.z * w0.z, v);
        m = fmaf(h3, w0.w, m); v = fmaf(h3 * h3, w0.w * w0.w, v);
        m = fmaf(h4, w1.x, m); v = fmaf(h4 * h4, w1.x * w1.x, v);
        m = fmaf(h5, w1.y, m); v = fmaf(h5 * h5, w1.y * w1.y, v);
        m = fmaf(h6, w1.z, m); v = fmaf(h6 * h6, w1.z * w1.z, v);
        m = fmaf(h7, w1.w, m); v = fmaf(h7 * h7, w1.w * w1.w, v);
      }
      float mean = 0.5f * m;
      float sd = 0.5f * sqrtf(v);
      uint32_t idx = (uint32_t)(gr0 + rl) * 10u + (uint32_t)c;
      float eps = eps_part(k2a, k2b, idx);
      out[(size_t)(gr0 + rl) * N_OUT + c] = mean + sd * (eps * INV);
    }
  }
}

extern "C" void kernel_launch(void* const* d_in, const int* in_sizes, int n_in,
                              void* d_out, int out_size, void* d_ws, size_t ws_size,
                              hipStream_t stream) {
  const float* x = (const float*)d_in[0];
  const float* W1 = (const float*)d_in[1];
  const float* W2 = (const float*)d_in[2];
  float* outp = (float*)d_out;
  u16* bp = (u16*)d_ws;  // needs 2*256*800*2 = 819200 B

  // k1, k2 = jax.random.split(jax.random.key(42)), partitionable threefry
  uint32_t k1a, k1b, k2a, k2b;
  threefry2x32(0u, 42u, 0u, 0u, k1a, k1b);
  threefry2x32(0u, 42u, 0u, 1u, k2a, k2b);

  pack_w1<<<256, 256, 0, stream>>>(W1, bp);
  fused_mfma<<<65536 / BM, 512, 0, stream>>>(x, bp, W2, outp, k1a, k1b, k2a, k2b);
}

// Round 5
// 789.349 us; speedup vs baseline: 1.0190x; 1.0190x over previous
//
#include <hip/hip_runtime.h>
#include <cstdint>

// Net_79139067396690: MC-dropout moment-propagation MLP, MFMA version.
//   h   = relu(0.5*x@W1^T + 0.5*sqrt((x^2)@(W1^2)^T) * eps1/sqrt(1000))
//   out =      0.5*h@W2^T + 0.5*sqrt((h^2)@(W2^2)^T) * eps2/sqrt(1000)
// GEMM1 on bf16 matrix cores (16x16x32), layer 2 + RNG on VALU.
// eps = jax.random.normal, partitionable threefry (verified round 2).
// Round 5: __launch_bounds__(512, 1). Rounds 3/4 spilled the ENTIRE 128-reg
// accumulator to scratch every K-step (WRITE_SIZE decoded exactly to
// 512B x nthreads x 25 steps) because (512,2) was interpreted as 2 blocks/CU
// -> 128-reg/wave budget. (512,1) -> 1 block/CU -> 256 regs; live set ~232.

#define K_DIM 784
#define KP 800                 // K padded to multiple of 32 in the W1 pack
#define N_HID 256
#define N_OUT 10
#define BM 128
#define NSTEP 25               // KP/32
#define WSQ_OFF (N_HID * KP)   // ushort offset of squared-W pack
#define HSTRIDE 264            // u16 stride of hbuf rows (16B-aligned, bank-safe)

using short8 = __attribute__((ext_vector_type(8))) short;
using floatx4 = __attribute__((ext_vector_type(4))) float;
typedef uint16_t u16;

// ---- Threefry-2x32 (JAX-compatible) ----
__host__ __device__ inline void threefry2x32(uint32_t k0, uint32_t k1,
                                             uint32_t x0, uint32_t x1,
                                             uint32_t& o0, uint32_t& o1) {
  uint32_t ks[3] = {k0, k1, k0 ^ k1 ^ 0x1BD11BDAu};
  x0 += ks[0];
  x1 += ks[1];
  const uint32_t rot[8] = {13u, 15u, 26u, 6u, 17u, 29u, 16u, 24u};
#pragma unroll
  for (int i = 0; i < 5; ++i) {
#pragma unroll
    for (int j = 0; j < 4; ++j) {
      uint32_t r = rot[(i & 1) * 4 + j];
      x0 += x1;
      x1 = (x1 << r) | (x1 >> (32u - r));
      x1 ^= x0;
    }
    x0 += ks[(i + 1) % 3];
    x1 += ks[(i + 2) % 3] + (uint32_t)(i + 1);
  }
  o0 = x0;
  o1 = x1;
}

// bits -> N(0,1), matching jax.random.normal (mantissa-uniform + Giles erfinv)
__device__ __forceinline__ float bits_to_normal(uint32_t bits) {
  const float lo = -0.99999994f;  // nextafterf(-1,0)
  float u01 = __uint_as_float((bits >> 9) | 0x3F800000u) - 1.0f;
  float u = fmaxf(lo, u01 * 2.0f + lo);
  float w = -log1pf(-u * u);
  float p;
  if (w < 5.0f) {
    w -= 2.5f;
    p = 2.81022636e-08f;
    p = fmaf(p, w, 3.43273939e-07f);
    p = fmaf(p, w, -3.5233877e-06f);
    p = fmaf(p, w, -4.39150654e-06f);
    p = fmaf(p, w, 0.00021858087f);
    p = fmaf(p, w, -0.00125372503f);
    p = fmaf(p, w, -0.00417768164f);
    p = fmaf(p, w, 0.246640727f);
    p = fmaf(p, w, 1.50140941f);
  } else {
    w = sqrtf(w) - 3.0f;
    p = -0.000200214257f;
    p = fmaf(p, w, 0.000100950558f);
    p = fmaf(p, w, 0.00134934322f);
    p = fmaf(p, w, -0.00367342844f);
    p = fmaf(p, w, 0.00573950773f);
    p = fmaf(p, w, -0.0076224613f);
    p = fmaf(p, w, 0.00943887047f);
    p = fmaf(p, w, 1.00167406f);
    p = fmaf(p, w, 2.83297682f);
  }
  return 1.41421356f * (p * u);
}

__device__ __forceinline__ float eps_part(uint32_t ka, uint32_t kb, uint32_t i) {
  uint32_t o0, o1;
  threefry2x32(ka, kb, 0u, i, o0, o1);
  return bits_to_normal(o0 ^ o1);
}

// f32 -> bf16 round-to-nearest-even
__host__ __device__ __forceinline__ u16 f2bf(float f) {
  uint32_t u;
#ifdef __HIP_DEVICE_COMPILE__
  u = __float_as_uint(f);
#else
  __builtin_memcpy(&u, &f, 4);
#endif
  return (u16)((u + 0x7FFFu + ((u >> 16) & 1u)) >> 16);
}

__device__ __forceinline__ float bf2f(u16 b) {
  return __uint_as_float((uint32_t)b << 16);
}

// ---- pre-pack W1 -> bf16 {w, w^2}, K padded to 800 with zeros ----
__global__ __launch_bounds__(256) void pack_w1(const float* __restrict__ W1,
                                               u16* __restrict__ bp) {
  const int col = blockIdx.x;  // 0..255
  for (int k = threadIdx.x; k < KP; k += 256) {
    float w = (k < K_DIM) ? W1[col * K_DIM + k] : 0.0f;
    bp[col * KP + k] = f2bf(w);
    bp[WSQ_OFF + col * KP + k] = f2bf(w * w);
  }
}

// ---- fused main kernel: one block = 128 batch rows, full N=256 ----
// launch_bounds (512, 1): 1 block/CU under EITHER interpretation of arg2
// -> per-wave unified-reg budget >= 256 -> accumulators stay in registers.
__global__ __launch_bounds__(512, 1) void fused_mfma(
    const float* __restrict__ x, const u16* __restrict__ bp,
    const float* __restrict__ W2, float* __restrict__ out,
    uint32_t k1a, uint32_t k1b, uint32_t k2a, uint32_t k2b) {
  __shared__ u16 sA[2][2][BM * 32];    // [dbuf][tensor: x, x^2][swizzled row*32+k]
  __shared__ u16 hbuf[BM * HSTRIDE];   // h (bf16)
  __shared__ float sW2[10 * 260];

  const int tid = threadIdx.x;
  const int lane = tid & 63;
  const int l15 = lane & 15;
  const int lhal = lane >> 4;  // 0..3
  const int wid = tid >> 6;    // 0..7
  const int wm = wid >> 2;     // 0..1  (m-direction)
  const int wn = wid & 3;      // 0..3  (n-direction)
  const int gr0 = blockIdx.x * BM;

  // --- staging geometry: thread -> (row, 8-wide k chunk) of the A tile ---
  const int srow = tid >> 2;         // 0..127
  const int skq = (tid & 3) * 8;     // 0,8,16,24
  const float* xptr = x + (size_t)(gr0 + srow) * K_DIM + skq;
  const int sidx = (srow * 32 + skq) ^ ((srow & 7) << 3);  // XOR swizzle (u16 units)

  // --- per-wave B offsets into the bf16 pack (u16 units, 32-bit) ---
  uint32_t boff[4];
#pragma unroll
  for (int j = 0; j < 4; ++j) {
    int col = wn * 64 + j * 16 + l15;
    boff[j] = (uint32_t)col * KP + (uint32_t)lhal * 8;
  }

  // --- per-wave A fragment LDS indices ---
  int aidx[4];
#pragma unroll
  for (int i = 0; i < 4; ++i) {
    int r = wm * 64 + i * 16 + l15;
    aidx[i] = (r * 32 + lhal * 8) ^ ((r & 7) << 3);
  }

  floatx4 accm[4][4], accv[4][4];
#pragma unroll
  for (int i = 0; i < 4; ++i)
#pragma unroll
    for (int j = 0; j < 4; ++j)
#pragma unroll
      for (int g = 0; g < 4; ++g) { accm[i][j][g] = 0.0f; accv[i][j][g] = 0.0f; }

  float4 q0, q1;
  auto loadX = [&](int kk) {
    if (kk + skq + 8 <= K_DIM) {  // K tail (784 = 24*32+16): zero-fill OOB chunks
      q0 = *reinterpret_cast<const float4*>(xptr + kk);
      q1 = *reinterpret_cast<const float4*>(xptr + kk + 4);
    } else {
      q0 = make_float4(0.f, 0.f, 0.f, 0.f);
      q1 = make_float4(0.f, 0.f, 0.f, 0.f);
    }
  };
  auto writeA = [&](int buf) {
    short8 va, v2;
    va[0] = (short)f2bf(q0.x); v2[0] = (short)f2bf(q0.x * q0.x);
    va[1] = (short)f2bf(q0.y); v2[1] = (short)f2bf(q0.y * q0.y);
    va[2] = (short)f2bf(q0.z); v2[2] = (short)f2bf(q0.z * q0.z);
    va[3] = (short)f2bf(q0.w); v2[3] = (short)f2bf(q0.w * q0.w);
    va[4] = (short)f2bf(q1.x); v2[4] = (short)f2bf(q1.x * q1.x);
    va[5] = (short)f2bf(q1.y); v2[5] = (short)f2bf(q1.y * q1.y);
    va[6] = (short)f2bf(q1.z); v2[6] = (short)f2bf(q1.z * q1.z);
    va[7] = (short)f2bf(q1.w); v2[7] = (short)f2bf(q1.w * q1.w);
    *reinterpret_cast<short8*>(&sA[buf][0][sidx]) = va;
    *reinterpret_cast<short8*>(&sA[buf][1][sidx]) = v2;
  };

  // prologue: stage step 0
  loadX(0);
  writeA(0);
  __syncthreads();

  for (int s = 0; s < NSTEP; ++s) {
    const int cur = s & 1, nxt = cur ^ 1;
    const bool have = (s + 1 < NSTEP);
    const int kk = s * 32;
    // B for this step, fresh from L2 (no prefetch regs — bounds the live set)
    short8 bmc[4], bvc[4];
#pragma unroll
    for (int j = 0; j < 4; ++j) {
      bmc[j] = *reinterpret_cast<const short8*>(&bp[boff[j] + kk]);
      bvc[j] = *reinterpret_cast<const short8*>(&bp[WSQ_OFF + boff[j] + kk]);
    }
    if (have) loadX(kk + 32);  // x prefetch (8 regs in flight)
    short8 af[4], avf[4];
#pragma unroll
    for (int i = 0; i < 4; ++i) {
      af[i] = *reinterpret_cast<const short8*>(&sA[cur][0][aidx[i]]);
      avf[i] = *reinterpret_cast<const short8*>(&sA[cur][1][aidx[i]]);
    }
#pragma unroll
    for (int i = 0; i < 4; ++i)
#pragma unroll
      for (int j = 0; j < 4; ++j) {
        accm[i][j] = __builtin_amdgcn_mfma_f32_16x16x32_bf16(af[i], bmc[j], accm[i][j], 0, 0, 0);
        accv[i][j] = __builtin_amdgcn_mfma_f32_16x16x32_bf16(avf[i], bvc[j], accv[i][j], 0, 0, 0);
      }
    if (have) writeA(nxt);  // convert + ds_write for next step
    __syncthreads();
  }

  // --- stage W2 (f32) ---
#pragma unroll
  for (int g = 0; g < 5; ++g) {
    int gg = tid + g * 512;  // 2560 = 5*512 exactly
    sW2[(gg >> 8) * 260 + (gg & 255)] = W2[gg];
  }

  // --- layer-1 epilogue: eps1 + relu -> hbuf (bf16) ---
  const float INV = 0.031622776601683794f;  // 1/sqrt(1000)
#pragma unroll
  for (int i = 0; i < 4; ++i)
#pragma unroll
    for (int j = 0; j < 4; ++j)
#pragma unroll
      for (int g = 0; g < 4; ++g) {
        int rl = wm * 64 + i * 16 + lhal * 4 + g;  // C/D: row=(lane>>4)*4+reg
        int c = wn * 64 + j * 16 + l15;            //      col=lane&15
        float mean = 0.5f * accm[i][j][g];
        float sd = 0.5f * sqrtf(accv[i][j][g]);
        uint32_t idx = (uint32_t)(gr0 + rl) * 256u + (uint32_t)c;
        float eps = eps_part(k1a, k1b, idx);
        float h = fmaxf(mean + sd * (eps * INV), 0.0f);
        hbuf[rl * HSTRIDE + c] = f2bf(h);
      }
  __syncthreads();

  // --- layer 2 (VALU): 128x10 outputs, K=256 from hbuf, short8-vectorized ---
#pragma unroll
  for (int it = 0; it < 3; ++it) {
    int item = tid + it * 512;
    if (item < BM * N_OUT) {
      int rl = item / N_OUT;
      int c = item - rl * N_OUT;
      float m = 0.0f, v = 0.0f;
#pragma unroll 4
      for (int k8 = 0; k8 < N_HID / 8; ++k8) {
        short8 hv = *reinterpret_cast<const short8*>(&hbuf[rl * HSTRIDE + k8 * 8]);
        const float4 w0 = *reinterpret_cast<const float4*>(&sW2[c * 260 + k8 * 8]);
        const float4 w1 = *reinterpret_cast<const float4*>(&sW2[c * 260 + k8 * 8 + 4]);
        float h0 = bf2f((u16)hv[0]), h1 = bf2f((u16)hv[1]);
        float h2 = bf2f((u16)hv[2]), h3 = bf2f((u16)hv[3]);
        float h4 = bf2f((u16)hv[4]), h5 = bf2f((u16)hv[5]);
        float h6 = bf2f((u16)hv[6]), h7 = bf2f((u16)hv[7]);
        m = fmaf(h0, w0.x, m); v = fmaf(h0 * h0, w0.x * w0.x, v);
        m = fmaf(h1, w0.y, m); v = fmaf(h1 * h1, w0.y * w0.y, v);
        m = fmaf(h2, w0.z, m); v = fmaf(h2 * h2, w0.z * w0.z, v);
        m = fmaf(h3, w0.w, m); v = fmaf(h3 * h3, w0.w * w0.w, v);
        m = fmaf(h4, w1.x, m); v = fmaf(h4 * h4, w1.x * w1.x, v);
        m = fmaf(h5, w1.y, m); v = fmaf(h5 * h5, w1.y * w1.y, v);
        m = fmaf(h6, w1.z, m); v = fmaf(h6 * h6, w1.z * w1.z, v);
        m = fmaf(h7, w1.w, m); v = fmaf(h7 * h7, w1.w * w1.w, v);
      }
      float mean = 0.5f * m;
      float sd = 0.5f * sqrtf(v);
      uint32_t idx = (uint32_t)(gr0 + rl) * 10u + (uint32_t)c;
      float eps = eps_part(k2a, k2b, idx);
      out[(size_t)(gr0 + rl) * N_OUT + c] = mean + sd * (eps * INV);
    }
  }
}

extern "C" void kernel_launch(void* const* d_in, const int* in_sizes, int n_in,
                              void* d_out, int out_size, void* d_ws, size_t ws_size,
                              hipStream_t stream) {
  const float* x = (const float*)d_in[0];
  const float* W1 = (const float*)d_in[1];
  const float* W2 = (const float*)d_in[2];
  float* outp = (float*)d_out;
  u16* bp = (u16*)d_ws;  // needs 2*256*800*2 = 819200 B

  // k1, k2 = jax.random.split(jax.random.key(42)), partitionable threefry
  uint32_t k1a, k1b, k2a, k2b;
  threefry2x32(0u, 42u, 0u, 0u, k1a, k1b);
  threefry2x32(0u, 42u, 0u, 1u, k2a, k2b);

  pack_w1<<<256, 256, 0, stream>>>(W1, bp);
  fused_mfma<<<65536 / BM, 512, 0, stream>>>(x, bp, W2, outp, k1a, k1b, k2a, k2b);
}

// Round 6
// 458.186 us; speedup vs baseline: 1.7555x; 1.7228x over previous
//
#include <hip/hip_runtime.h>
#include <cstdint>

// Net_79139067396690: MC-dropout moment-propagation MLP, MFMA version.
//   h   = relu(0.5*x@W1^T + 0.5*sqrt((x^2)@(W1^2)^T) * eps1/sqrt(1000))
//   out =      0.5*h@W2^T + 0.5*sqrt((h^2)@(W2^2)^T) * eps2/sqrt(1000)
// Round 6: rounds 3-5 all spilled the accumulators because the floatx4
// acc[4][4] arrays stayed in an alloca (SROA runs before pragma-unroll
// resolves [i][j]; WRITE_SIZE decoded to exactly 26 x 512B per thread).
// Fix per rule #20: NAMED accumulators (am00..av33), macro-expanded MFMAs,
// literal vector subscripts in the epilogue. No register arrays anywhere.

#define K_DIM 784
#define KP 800                 // K padded to multiple of 32 in the W1 pack
#define N_HID 256
#define N_OUT 10
#define BM 128
#define NSTEP 25               // KP/32
#define WSQ_OFF (N_HID * KP)   // u16 offset of squared-W pack
#define HSTRIDE 264            // u16 stride of hbuf rows (16B-aligned)

using short8 = __attribute__((ext_vector_type(8))) short;
using floatx4 = __attribute__((ext_vector_type(4))) float;
typedef uint16_t u16;

// ---- Threefry-2x32 (JAX-compatible) ----
__host__ __device__ inline void threefry2x32(uint32_t k0, uint32_t k1,
                                             uint32_t x0, uint32_t x1,
                                             uint32_t& o0, uint32_t& o1) {
  uint32_t ks0 = k0, ks1 = k1, ks2 = k0 ^ k1 ^ 0x1BD11BDAu;
  x0 += ks0;
  x1 += ks1;
#define TFR(r) { x0 += x1; x1 = (x1 << (r)) | (x1 >> (32 - (r))); x1 ^= x0; }
  TFR(13) TFR(15) TFR(26) TFR(6)   x0 += ks1; x1 += ks2 + 1u;
  TFR(17) TFR(29) TFR(16) TFR(24)  x0 += ks2; x1 += ks0 + 2u;
  TFR(13) TFR(15) TFR(26) TFR(6)   x0 += ks0; x1 += ks1 + 3u;
  TFR(17) TFR(29) TFR(16) TFR(24)  x0 += ks1; x1 += ks2 + 4u;
  TFR(13) TFR(15) TFR(26) TFR(6)   x0 += ks2; x1 += ks0 + 5u;
#undef TFR
  o0 = x0;
  o1 = x1;
}

// bits -> N(0,1), matching jax.random.normal (mantissa-uniform + Giles erfinv)
__device__ __forceinline__ float bits_to_normal(uint32_t bits) {
  const float lo = -0.99999994f;  // nextafterf(-1,0)
  float u01 = __uint_as_float((bits >> 9) | 0x3F800000u) - 1.0f;
  float u = fmaxf(lo, u01 * 2.0f + lo);
  float w = -log1pf(-u * u);
  float p;
  if (w < 5.0f) {
    w -= 2.5f;
    p = 2.81022636e-08f;
    p = fmaf(p, w, 3.43273939e-07f);
    p = fmaf(p, w, -3.5233877e-06f);
    p = fmaf(p, w, -4.39150654e-06f);
    p = fmaf(p, w, 0.00021858087f);
    p = fmaf(p, w, -0.00125372503f);
    p = fmaf(p, w, -0.00417768164f);
    p = fmaf(p, w, 0.246640727f);
    p = fmaf(p, w, 1.50140941f);
  } else {
    w = sqrtf(w) - 3.0f;
    p = -0.000200214257f;
    p = fmaf(p, w, 0.000100950558f);
    p = fmaf(p, w, 0.00134934322f);
    p = fmaf(p, w, -0.00367342844f);
    p = fmaf(p, w, 0.00573950773f);
    p = fmaf(p, w, -0.0076224613f);
    p = fmaf(p, w, 0.00943887047f);
    p = fmaf(p, w, 1.00167406f);
    p = fmaf(p, w, 2.83297682f);
  }
  return 1.41421356f * (p * u);
}

__device__ __forceinline__ float eps_part(uint32_t ka, uint32_t kb, uint32_t i) {
  uint32_t o0, o1;
  threefry2x32(ka, kb, 0u, i, o0, o1);
  return bits_to_normal(o0 ^ o1);
}

// f32 -> bf16 round-to-nearest-even
__host__ __device__ __forceinline__ u16 f2bf(float f) {
  uint32_t u;
#ifdef __HIP_DEVICE_COMPILE__
  u = __float_as_uint(f);
#else
  __builtin_memcpy(&u, &f, 4);
#endif
  return (u16)((u + 0x7FFFu + ((u >> 16) & 1u)) >> 16);
}

__device__ __forceinline__ float bf2f(u16 b) {
  return __uint_as_float((uint32_t)b << 16);
}

// ---- pre-pack W1 -> bf16 {w, w^2}, K padded to 800 with zeros ----
__global__ __launch_bounds__(256) void pack_w1(const float* __restrict__ W1,
                                               u16* __restrict__ bp) {
  const int col = blockIdx.x;  // 0..255
  for (int k = threadIdx.x; k < KP; k += 256) {
    float w = (k < K_DIM) ? W1[col * K_DIM + k] : 0.0f;
    bp[col * KP + k] = f2bf(w);
    bp[WSQ_OFF + col * KP + k] = f2bf(w * w);
  }
}

// ---- fused main kernel: one block = 128 batch rows, full N=256 ----
__global__ __launch_bounds__(512, 2) void fused_mfma(
    const float* __restrict__ x, const u16* __restrict__ bp,
    const float* __restrict__ W2, float* __restrict__ out,
    uint32_t k1a, uint32_t k1b, uint32_t k2a, uint32_t k2b) {
  __shared__ u16 sA[2][2][BM * 32];    // [dbuf][tensor: x, x^2][swizzled row*32+k]
  __shared__ u16 hbuf[BM * HSTRIDE];   // h (bf16)
  __shared__ float sW2[10 * 260];

  const int tid = threadIdx.x;
  const int lane = tid & 63;
  const int l15 = lane & 15;
  const int lhal = lane >> 4;  // 0..3
  const int wid = tid >> 6;    // 0..7
  const int wm = wid >> 2;     // 0..1  (m-direction)
  const int wn = wid & 3;      // 0..3  (n-direction)
  const int gr0 = blockIdx.x * BM;

  // --- staging geometry: thread -> (row, 8-wide k chunk) of the A tile ---
  const int srow = tid >> 2;         // 0..127
  const int skq = (tid & 3) * 8;     // 0,8,16,24
  const float* xptr = x + (size_t)(gr0 + srow) * K_DIM + skq;
  const int sidx = (srow * 32 + skq) ^ ((srow & 7) << 3);  // XOR swizzle (u16 units)

  // --- per-wave B offsets into the bf16 pack (u16 units), NAMED ---
  const uint32_t boff0 = (uint32_t)(wn * 64 + 0 * 16 + l15) * KP + (uint32_t)lhal * 8;
  const uint32_t boff1 = (uint32_t)(wn * 64 + 1 * 16 + l15) * KP + (uint32_t)lhal * 8;
  const uint32_t boff2 = (uint32_t)(wn * 64 + 2 * 16 + l15) * KP + (uint32_t)lhal * 8;
  const uint32_t boff3 = (uint32_t)(wn * 64 + 3 * 16 + l15) * KP + (uint32_t)lhal * 8;

  // --- per-wave A fragment LDS indices, NAMED ---
#define AIDX(i) ((((wm * 64 + i * 16 + l15) * 32 + lhal * 8)) ^ (((wm * 64 + i * 16 + l15) & 7) << 3))
  const int aidx0 = AIDX(0);
  const int aidx1 = AIDX(1);
  const int aidx2 = AIDX(2);
  const int aidx3 = AIDX(3);
#undef AIDX

  // --- NAMED accumulators (no arrays -> no alloca -> no scratch) ---
#define DECL_ACC(i, j) \
  floatx4 am##i##j = {0.f, 0.f, 0.f, 0.f}; \
  floatx4 av##i##j = {0.f, 0.f, 0.f, 0.f};
  DECL_ACC(0, 0) DECL_ACC(0, 1) DECL_ACC(0, 2) DECL_ACC(0, 3)
  DECL_ACC(1, 0) DECL_ACC(1, 1) DECL_ACC(1, 2) DECL_ACC(1, 3)
  DECL_ACC(2, 0) DECL_ACC(2, 1) DECL_ACC(2, 2) DECL_ACC(2, 3)
  DECL_ACC(3, 0) DECL_ACC(3, 1) DECL_ACC(3, 2) DECL_ACC(3, 3)
#undef DECL_ACC

  float4 q0, q1;
  auto loadX = [&](int kk) {
    if (kk + skq + 8 <= K_DIM) {  // K tail (784 = 24*32+16): zero-fill OOB chunks
      q0 = *reinterpret_cast<const float4*>(xptr + kk);
      q1 = *reinterpret_cast<const float4*>(xptr + kk + 4);
    } else {
      q0 = make_float4(0.f, 0.f, 0.f, 0.f);
      q1 = make_float4(0.f, 0.f, 0.f, 0.f);
    }
  };
  auto writeA = [&](int buf) {
    short8 va, v2;
    va[0] = (short)f2bf(q0.x); v2[0] = (short)f2bf(q0.x * q0.x);
    va[1] = (short)f2bf(q0.y); v2[1] = (short)f2bf(q0.y * q0.y);
    va[2] = (short)f2bf(q0.z); v2[2] = (short)f2bf(q0.z * q0.z);
    va[3] = (short)f2bf(q0.w); v2[3] = (short)f2bf(q0.w * q0.w);
    va[4] = (short)f2bf(q1.x); v2[4] = (short)f2bf(q1.x * q1.x);
    va[5] = (short)f2bf(q1.y); v2[5] = (short)f2bf(q1.y * q1.y);
    va[6] = (short)f2bf(q1.z); v2[6] = (short)f2bf(q1.z * q1.z);
    va[7] = (short)f2bf(q1.w); v2[7] = (short)f2bf(q1.w * q1.w);
    *reinterpret_cast<short8*>(&sA[buf][0][sidx]) = va;
    *reinterpret_cast<short8*>(&sA[buf][1][sidx]) = v2;
  };

  // prologue: stage step 0
  loadX(0);
  writeA(0);
  __syncthreads();

  for (int s = 0; s < NSTEP; ++s) {
    const int cur = s & 1, nxt = cur ^ 1;
    const bool have = (s + 1 < NSTEP);
    const int kk = s * 32;

    // B for this step, fresh from L2 (L2-resident 819 KB pack), NAMED frags
    const u16* bpk = bp + kk;
    const short8 bm0 = *reinterpret_cast<const short8*>(&bpk[boff0]);
    const short8 bm1 = *reinterpret_cast<const short8*>(&bpk[boff1]);
    const short8 bm2 = *reinterpret_cast<const short8*>(&bpk[boff2]);
    const short8 bm3 = *reinterpret_cast<const short8*>(&bpk[boff3]);
    const short8 bv0 = *reinterpret_cast<const short8*>(&bpk[WSQ_OFF + boff0]);
    const short8 bv1 = *reinterpret_cast<const short8*>(&bpk[WSQ_OFF + boff1]);
    const short8 bv2 = *reinterpret_cast<const short8*>(&bpk[WSQ_OFF + boff2]);
    const short8 bv3 = *reinterpret_cast<const short8*>(&bpk[WSQ_OFF + boff3]);

    if (have) loadX(kk + 32);  // x prefetch

    const u16* sc0 = &sA[cur][0][0];
    const u16* sc1 = &sA[cur][1][0];
    const short8 af0 = *reinterpret_cast<const short8*>(&sc0[aidx0]);
    const short8 af1 = *reinterpret_cast<const short8*>(&sc0[aidx1]);
    const short8 af2 = *reinterpret_cast<const short8*>(&sc0[aidx2]);
    const short8 af3 = *reinterpret_cast<const short8*>(&sc0[aidx3]);
    const short8 ag0 = *reinterpret_cast<const short8*>(&sc1[aidx0]);
    const short8 ag1 = *reinterpret_cast<const short8*>(&sc1[aidx1]);
    const short8 ag2 = *reinterpret_cast<const short8*>(&sc1[aidx2]);
    const short8 ag3 = *reinterpret_cast<const short8*>(&sc1[aidx3]);

#define MFMA_IJ(i, j) \
    am##i##j = __builtin_amdgcn_mfma_f32_16x16x32_bf16(af##i, bm##j, am##i##j, 0, 0, 0); \
    av##i##j = __builtin_amdgcn_mfma_f32_16x16x32_bf16(ag##i, bv##j, av##i##j, 0, 0, 0);
    MFMA_IJ(0, 0) MFMA_IJ(0, 1) MFMA_IJ(0, 2) MFMA_IJ(0, 3)
    MFMA_IJ(1, 0) MFMA_IJ(1, 1) MFMA_IJ(1, 2) MFMA_IJ(1, 3)
    MFMA_IJ(2, 0) MFMA_IJ(2, 1) MFMA_IJ(2, 2) MFMA_IJ(2, 3)
    MFMA_IJ(3, 0) MFMA_IJ(3, 1) MFMA_IJ(3, 2) MFMA_IJ(3, 3)
#undef MFMA_IJ

    if (have) writeA(nxt);  // convert + ds_write for next step
    __syncthreads();
  }

  // --- stage W2 (f32) ---
#pragma unroll
  for (int g = 0; g < 5; ++g) {
    int gg = tid + g * 512;  // 2560 = 5*512 exactly
    sW2[(gg >> 8) * 260 + (gg & 255)] = W2[gg];
  }

  // --- layer-1 epilogue: eps1 + relu -> hbuf (bf16); literal subscripts ---
  const float INV = 0.031622776601683794f;  // 1/sqrt(1000)
#define EPIG(AM, AV, G, RL, C) do { \
    float mean_ = 0.5f * (AM)[G]; \
    float sd_ = 0.5f * sqrtf((AV)[G]); \
    uint32_t idx_ = (uint32_t)(gr0 + (RL) + (G)) * 256u + (uint32_t)(C); \
    float eps_ = eps_part(k1a, k1b, idx_); \
    float h_ = fmaxf(mean_ + sd_ * (eps_ * INV), 0.0f); \
    hbuf[((RL) + (G)) * HSTRIDE + (C)] = f2bf(h_); \
  } while (0)
#define EPI(i, j) do { \
    const int rl_ = wm * 64 + i * 16 + lhal * 4; \
    const int c_ = wn * 64 + j * 16 + l15; \
    EPIG(am##i##j, av##i##j, 0, rl_, c_); \
    EPIG(am##i##j, av##i##j, 1, rl_, c_); \
    EPIG(am##i##j, av##i##j, 2, rl_, c_); \
    EPIG(am##i##j, av##i##j, 3, rl_, c_); \
  } while (0)
  EPI(0, 0); EPI(0, 1); EPI(0, 2); EPI(0, 3);
  EPI(1, 0); EPI(1, 1); EPI(1, 2); EPI(1, 3);
  EPI(2, 0); EPI(2, 1); EPI(2, 2); EPI(2, 3);
  EPI(3, 0); EPI(3, 1); EPI(3, 2); EPI(3, 3);
#undef EPI
#undef EPIG
  __syncthreads();

  // --- layer 2 (VALU): 128x10 outputs, K=256 from hbuf, short8-vectorized ---
#pragma unroll
  for (int it = 0; it < 3; ++it) {
    int item = tid + it * 512;
    if (item < BM * N_OUT) {
      int rl = item / N_OUT;
      int c = item - rl * N_OUT;
      float m = 0.0f, v = 0.0f;
#pragma unroll 4
      for (int k8 = 0; k8 < N_HID / 8; ++k8) {
        short8 hv = *reinterpret_cast<const short8*>(&hbuf[rl * HSTRIDE + k8 * 8]);
        const float4 w0 = *reinterpret_cast<const float4*>(&sW2[c * 260 + k8 * 8]);
        const float4 w1 = *reinterpret_cast<const float4*>(&sW2[c * 260 + k8 * 8 + 4]);
        float h0 = bf2f((u16)hv[0]), h1 = bf2f((u16)hv[1]);
        float h2 = bf2f((u16)hv[2]), h3 = bf2f((u16)hv[3]);
        float h4 = bf2f((u16)hv[4]), h5 = bf2f((u16)hv[5]);
        float h6 = bf2f((u16)hv[6]), h7 = bf2f((u16)hv[7]);
        m = fmaf(h0, w0.x, m); v = fmaf(h0 * h0, w0.x * w0.x, v);
        m = fmaf(h1, w0.y, m); v = fmaf(h1 * h1, w0.y * w0.y, v);
        m = fmaf(h2, w0.z, m); v = fmaf(h2 * h2, w0.z * w0.z, v);
        m = fmaf(h3, w0.w, m); v = fmaf(h3 * h3, w0.w * w0.w, v);
        m = fmaf(h4, w1.x, m); v = fmaf(h4 * h4, w1.x * w1.x, v);
        m = fmaf(h5, w1.y, m); v = fmaf(h5 * h5, w1.y * w1.y, v);
        m = fmaf(h6, w1.z, m); v = fmaf(h6 * h6, w1.z * w1.z, v);
        m = fmaf(h7, w1.w, m); v = fmaf(h7 * h7, w1.w * w1.w, v);
      }
      float mean = 0.5f * m;
      float sd = 0.5f * sqrtf(v);
      uint32_t idx = (uint32_t)(gr0 + rl) * 10u + (uint32_t)c;
      float eps = eps_part(k2a, k2b, idx);
      out[(size_t)(gr0 + rl) * N_OUT + c] = mean + sd * (eps * INV);
    }
  }
}

extern "C" void kernel_launch(void* const* d_in, const int* in_sizes, int n_in,
                              void* d_out, int out_size, void* d_ws, size_t ws_size,
                              hipStream_t stream) {
  const float* x = (const float*)d_in[0];
  const float* W1 = (const float*)d_in[1];
  const float* W2 = (const float*)d_in[2];
  float* outp = (float*)d_out;
  u16* bp = (u16*)d_ws;  // needs 2*256*800*2 = 819200 B

  // k1, k2 = jax.random.split(jax.random.key(42)), partitionable threefry
  uint32_t k1a, k1b, k2a, k2b;
  threefry2x32(0u, 42u, 0u, 0u, k1a, k1b);
  threefry2x32(0u, 42u, 0u, 1u, k2a, k2b);

  pack_w1<<<256, 256, 0, stream>>>(W1, bp);
  fused_mfma<<<65536 / BM, 512, 0, stream>>>(x, bp, W2, outp, k1a, k1b, k2a, k2b);
}

// Round 7
// 248.923 us; speedup vs baseline: 3.2313x; 1.8407x over previous
//
#include <hip/hip_runtime.h>
#include <cstdint>

// Net_79139067396690: MC-dropout moment-propagation MLP.
//   h   = relu(0.5*x@W1^T + 0.5*sqrt((x^2)@(W1^2)^T) * eps1/sqrt(1000))
//   out =      0.5*h@W2^T + 0.5*sqrt((h^2)@(W2^2)^T) * eps2/sqrt(1000)
// Round 7: occupancy. R6 was latency-bound at 8 waves/CU (LDS 111KB -> 1
// block/CU; 244 unified regs -> 2 waves/SIMD). Split layer2 into its own
// kernel (h via d_ws), shrink wave tile to 64x32 (64 acc regs), 256-thr
// blocks, target <=128 regs -> 4 waves/SIMD, 4 independent blocks/CU.
// All register state NAMED (rule #20 — r3-r5 alloca spill lesson).

#define K_DIM 784
#define KP 800                 // K padded to multiple of 32 in the W1 pack
#define N_HID 256
#define N_OUT 10
#define BM 64                  // rows per block
#define NSTEP 25               // KP/32
#define WSQ_OFF (N_HID * KP)   // u16 offset of squared-W pack
#define H_OFF (1 << 20)        // byte offset of h in d_ws

using short8 = __attribute__((ext_vector_type(8))) short;
using floatx4 = __attribute__((ext_vector_type(4))) float;
typedef uint16_t u16;

// ---- Threefry-2x32 (JAX-compatible) ----
__host__ __device__ inline void threefry2x32(uint32_t k0, uint32_t k1,
                                             uint32_t x0, uint32_t x1,
                                             uint32_t& o0, uint32_t& o1) {
  uint32_t ks0 = k0, ks1 = k1, ks2 = k0 ^ k1 ^ 0x1BD11BDAu;
  x0 += ks0;
  x1 += ks1;
#define TFR(r) { x0 += x1; x1 = (x1 << (r)) | (x1 >> (32 - (r))); x1 ^= x0; }
  TFR(13) TFR(15) TFR(26) TFR(6)   x0 += ks1; x1 += ks2 + 1u;
  TFR(17) TFR(29) TFR(16) TFR(24)  x0 += ks2; x1 += ks0 + 2u;
  TFR(13) TFR(15) TFR(26) TFR(6)   x0 += ks0; x1 += ks1 + 3u;
  TFR(17) TFR(29) TFR(16) TFR(24)  x0 += ks1; x1 += ks2 + 4u;
  TFR(13) TFR(15) TFR(26) TFR(6)   x0 += ks2; x1 += ks0 + 5u;
#undef TFR
  o0 = x0;
  o1 = x1;
}

// bits -> N(0,1), matching jax.random.normal (mantissa-uniform + Giles erfinv)
__device__ __forceinline__ float bits_to_normal(uint32_t bits) {
  const float lo = -0.99999994f;  // nextafterf(-1,0)
  float u01 = __uint_as_float((bits >> 9) | 0x3F800000u) - 1.0f;
  float u = fmaxf(lo, u01 * 2.0f + lo);
  float w = -log1pf(-u * u);
  float p;
  if (w < 5.0f) {
    w -= 2.5f;
    p = 2.81022636e-08f;
    p = fmaf(p, w, 3.43273939e-07f);
    p = fmaf(p, w, -3.5233877e-06f);
    p = fmaf(p, w, -4.39150654e-06f);
    p = fmaf(p, w, 0.00021858087f);
    p = fmaf(p, w, -0.00125372503f);
    p = fmaf(p, w, -0.00417768164f);
    p = fmaf(p, w, 0.246640727f);
    p = fmaf(p, w, 1.50140941f);
  } else {
    w = sqrtf(w) - 3.0f;
    p = -0.000200214257f;
    p = fmaf(p, w, 0.000100950558f);
    p = fmaf(p, w, 0.00134934322f);
    p = fmaf(p, w, -0.00367342844f);
    p = fmaf(p, w, 0.00573950773f);
    p = fmaf(p, w, -0.0076224613f);
    p = fmaf(p, w, 0.00943887047f);
    p = fmaf(p, w, 1.00167406f);
    p = fmaf(p, w, 2.83297682f);
  }
  return 1.41421356f * (p * u);
}

__device__ __forceinline__ float eps_part(uint32_t ka, uint32_t kb, uint32_t i) {
  uint32_t o0, o1;
  threefry2x32(ka, kb, 0u, i, o0, o1);
  return bits_to_normal(o0 ^ o1);
}

// f32 -> bf16 round-to-nearest-even
__host__ __device__ __forceinline__ u16 f2bf(float f) {
  uint32_t u;
#ifdef __HIP_DEVICE_COMPILE__
  u = __float_as_uint(f);
#else
  __builtin_memcpy(&u, &f, 4);
#endif
  return (u16)((u + 0x7FFFu + ((u >> 16) & 1u)) >> 16);
}

__device__ __forceinline__ float bf2f(u16 b) {
  return __uint_as_float((uint32_t)b << 16);
}

// ---- pre-pack W1 -> bf16 {w, w^2}, K padded to 800 with zeros ----
__global__ __launch_bounds__(256) void pack_w1(const float* __restrict__ W1,
                                               u16* __restrict__ bp) {
  const int col = blockIdx.x;  // 0..255
  for (int k = threadIdx.x; k < KP; k += 256) {
    float w = (k < K_DIM) ? W1[col * K_DIM + k] : 0.0f;
    bp[col * KP + k] = f2bf(w);
    bp[WSQ_OFF + col * KP + k] = f2bf(w * w);
  }
}

// ---- GEMM1 + eps1 + relu -> h (bf16, global) ----
// Block: 256 thr = 4 waves; BM=64 rows x BN=128 cols; wave = 64 x 32.
// Grid: (65536/64) row-tiles x 2 col-tiles = 2048 blocks.
__global__ __launch_bounds__(256, 4) void gemm1(
    const float* __restrict__ x, const u16* __restrict__ bp,
    u16* __restrict__ hws, uint32_t k1a, uint32_t k1b) {
  __shared__ u16 sA[2][2][BM * 32];  // [dbuf][x, x^2][swizzled row*32+k] 16KB

  const int tid = threadIdx.x;
  const int lane = tid & 63;
  const int l15 = lane & 15;
  const int lhal = lane >> 4;      // 0..3
  const int wn = tid >> 6;         // wave id 0..3 -> 32-col strip
  const int bid = blockIdx.x;
  const int gr0 = (bid >> 1) * BM;        // row origin
  const int bc0 = (bid & 1) * 128;        // col origin

  // staging: thread -> (row 0..63, 8-wide k chunk)
  const int srow = tid >> 2;
  const int skq = (tid & 3) * 8;
  const float* xptr = x + (size_t)(gr0 + srow) * K_DIM + skq;
  const int sidx = (srow * 32 + skq) ^ ((srow & 7) << 3);

  // B offsets (u16 units) for this wave's two 16-col fragments
  const uint32_t boff0 = (uint32_t)(bc0 + wn * 32 + 0 * 16 + l15) * KP + (uint32_t)lhal * 8;
  const uint32_t boff1 = (uint32_t)(bc0 + wn * 32 + 1 * 16 + l15) * KP + (uint32_t)lhal * 8;

  // A fragment LDS indices (rows i*16 + l15, k-group lhal*8), NAMED
#define AIDX(i) ((((i * 16 + l15) * 32 + lhal * 8)) ^ (((i * 16 + l15) & 7) << 3))
  const int aidx0 = AIDX(0);
  const int aidx1 = AIDX(1);
  const int aidx2 = AIDX(2);
  const int aidx3 = AIDX(3);
#undef AIDX

  // NAMED accumulators: am{i}{j}, av{i}{j}, i=0..3, j=0..1  (64 regs total)
#define DECL_ACC(i) \
  floatx4 am##i##0 = {0.f, 0.f, 0.f, 0.f}, am##i##1 = {0.f, 0.f, 0.f, 0.f}; \
  floatx4 av##i##0 = {0.f, 0.f, 0.f, 0.f}, av##i##1 = {0.f, 0.f, 0.f, 0.f};
  DECL_ACC(0) DECL_ACC(1) DECL_ACC(2) DECL_ACC(3)
#undef DECL_ACC

  float4 q0, q1;
  auto loadX = [&](int kk) {
    if (kk + skq + 8 <= K_DIM) {  // zero-fill the 784..799 tail
      q0 = *reinterpret_cast<const float4*>(xptr + kk);
      q1 = *reinterpret_cast<const float4*>(xptr + kk + 4);
    } else {
      q0 = make_float4(0.f, 0.f, 0.f, 0.f);
      q1 = make_float4(0.f, 0.f, 0.f, 0.f);
    }
  };
  auto writeA = [&](int buf) {
    short8 va, v2;
    va[0] = (short)f2bf(q0.x); v2[0] = (short)f2bf(q0.x * q0.x);
    va[1] = (short)f2bf(q0.y); v2[1] = (short)f2bf(q0.y * q0.y);
    va[2] = (short)f2bf(q0.z); v2[2] = (short)f2bf(q0.z * q0.z);
    va[3] = (short)f2bf(q0.w); v2[3] = (short)f2bf(q0.w * q0.w);
    va[4] = (short)f2bf(q1.x); v2[4] = (short)f2bf(q1.x * q1.x);
    va[5] = (short)f2bf(q1.y); v2[5] = (short)f2bf(q1.y * q1.y);
    va[6] = (short)f2bf(q1.z); v2[6] = (short)f2bf(q1.z * q1.z);
    va[7] = (short)f2bf(q1.w); v2[7] = (short)f2bf(q1.w * q1.w);
    *reinterpret_cast<short8*>(&sA[buf][0][sidx]) = va;
    *reinterpret_cast<short8*>(&sA[buf][1][sidx]) = v2;
  };

  loadX(0);
  writeA(0);
  __syncthreads();

  for (int s = 0; s < NSTEP; ++s) {
    const int cur = s & 1, nxt = cur ^ 1;
    const bool have = (s + 1 < NSTEP);
    const int kk = s * 32;

    const u16* bpk = bp + kk;
    const short8 bm0 = *reinterpret_cast<const short8*>(&bpk[boff0]);
    const short8 bm1 = *reinterpret_cast<const short8*>(&bpk[boff1]);
    const short8 bv0 = *reinterpret_cast<const short8*>(&bpk[WSQ_OFF + boff0]);
    const short8 bv1 = *reinterpret_cast<const short8*>(&bpk[WSQ_OFF + boff1]);

    if (have) loadX(kk + 32);

    const u16* sc0 = &sA[cur][0][0];
    const u16* sc1 = &sA[cur][1][0];
#define STEP_I(i) { \
    const short8 af = *reinterpret_cast<const short8*>(&sc0[aidx##i]); \
    const short8 ag = *reinterpret_cast<const short8*>(&sc1[aidx##i]); \
    am##i##0 = __builtin_amdgcn_mfma_f32_16x16x32_bf16(af, bm0, am##i##0, 0, 0, 0); \
    av##i##0 = __builtin_amdgcn_mfma_f32_16x16x32_bf16(ag, bv0, av##i##0, 0, 0, 0); \
    am##i##1 = __builtin_amdgcn_mfma_f32_16x16x32_bf16(af, bm1, am##i##1, 0, 0, 0); \
    av##i##1 = __builtin_amdgcn_mfma_f32_16x16x32_bf16(ag, bv1, av##i##1, 0, 0, 0); }
    STEP_I(0) STEP_I(1) STEP_I(2) STEP_I(3)
#undef STEP_I

    if (have) writeA(nxt);
    __syncthreads();
  }

  // epilogue: eps1 + relu -> h (bf16) in global ws
  const float INV = 0.031622776601683794f;  // 1/sqrt(1000)
#define EPIG(AM, AV, G, I, J) do { \
    const int rl_ = I * 16 + lhal * 4 + (G); \
    const int c_ = bc0 + wn * 32 + J * 16 + l15; \
    float mean_ = 0.5f * (AM)[G]; \
    float sd_ = 0.5f * sqrtf((AV)[G]); \
    uint32_t idx_ = (uint32_t)(gr0 + rl_) * 256u + (uint32_t)c_; \
    float eps_ = eps_part(k1a, k1b, idx_); \
    float h_ = fmaxf(mean_ + sd_ * (eps_ * INV), 0.0f); \
    hws[(size_t)(gr0 + rl_) * 256 + c_] = f2bf(h_); \
  } while (0)
#define EPI(i, j) do { \
    EPIG(am##i##j, av##i##j, 0, i, j); \
    EPIG(am##i##j, av##i##j, 1, i, j); \
    EPIG(am##i##j, av##i##j, 2, i, j); \
    EPIG(am##i##j, av##i##j, 3, i, j); \
  } while (0)
  EPI(0, 0); EPI(0, 1); EPI(1, 0); EPI(1, 1);
  EPI(2, 0); EPI(2, 1); EPI(3, 0); EPI(3, 1);
#undef EPI
#undef EPIG
}

// ---- layer 2: out = 0.5*h@W2^T + 0.5*sqrt((h^2)@(W2^2)^T)*eps2/sqrt(Z) ----
// Block: 256 thr = 64 rows x 4-way k-split. Grid: 1024 blocks.
__global__ __launch_bounds__(256, 4) void layer2(
    const u16* __restrict__ hws, const float* __restrict__ W2,
    float* __restrict__ out, uint32_t k2a, uint32_t k2b) {
  __shared__ float sW2[10 * 260];

  const int tid = threadIdx.x;
#pragma unroll
  for (int g = 0; g < 10; ++g) {
    int gg = tid + g * 256;  // 2560 = 10*256
    sW2[(gg >> 8) * 260 + (gg & 255)] = W2[gg];
  }
  __syncthreads();

  const int rloc = tid >> 2;   // 0..63
  const int ks = tid & 3;      // k-split quarter
  const int r = blockIdx.x * 64 + rloc;
  const u16* hrow = hws + (size_t)r * 256 + ks * 64;

  float mm[10], vv[10];
#pragma unroll
  for (int c = 0; c < 10; ++c) { mm[c] = 0.f; vv[c] = 0.f; }

#pragma unroll
  for (int ch = 0; ch < 8; ++ch) {
    const short8 hv = *reinterpret_cast<const short8*>(&hrow[ch * 8]);
    const float h0 = bf2f((u16)hv[0]), h1 = bf2f((u16)hv[1]);
    const float h2 = bf2f((u16)hv[2]), h3 = bf2f((u16)hv[3]);
    const float h4 = bf2f((u16)hv[4]), h5 = bf2f((u16)hv[5]);
    const float h6 = bf2f((u16)hv[6]), h7 = bf2f((u16)hv[7]);
    const float s0 = h0 * h0, s1 = h1 * h1, s2 = h2 * h2, s3 = h3 * h3;
    const float s4 = h4 * h4, s5 = h5 * h5, s6 = h6 * h6, s7 = h7 * h7;
    const int kb = ks * 64 + ch * 8;
#pragma unroll
    for (int c = 0; c < 10; ++c) {
      const float4 w0 = *reinterpret_cast<const float4*>(&sW2[c * 260 + kb]);
      const float4 w1 = *reinterpret_cast<const float4*>(&sW2[c * 260 + kb + 4]);
      mm[c] = fmaf(h0, w0.x, mm[c]); vv[c] = fmaf(s0, w0.x * w0.x, vv[c]);
      mm[c] = fmaf(h1, w0.y, mm[c]); vv[c] = fmaf(s1, w0.y * w0.y, vv[c]);
      mm[c] = fmaf(h2, w0.z, mm[c]); vv[c] = fmaf(s2, w0.z * w0.z, vv[c]);
      mm[c] = fmaf(h3, w0.w, mm[c]); vv[c] = fmaf(s3, w0.w * w0.w, vv[c]);
      mm[c] = fmaf(h4, w1.x, mm[c]); vv[c] = fmaf(s4, w1.x * w1.x, vv[c]);
      mm[c] = fmaf(h5, w1.y, mm[c]); vv[c] = fmaf(s5, w1.y * w1.y, vv[c]);
      mm[c] = fmaf(h6, w1.z, mm[c]); vv[c] = fmaf(s6, w1.z * w1.z, vv[c]);
      mm[c] = fmaf(h7, w1.w, mm[c]); vv[c] = fmaf(s7, w1.w * w1.w, vv[c]);
    }
  }

  // reduce across the 4-lane k-split (all 4 lanes end with full sums)
#pragma unroll
  for (int c = 0; c < 10; ++c) {
    mm[c] += __shfl_xor(mm[c], 1); mm[c] += __shfl_xor(mm[c], 2);
    vv[c] += __shfl_xor(vv[c], 1); vv[c] += __shfl_xor(vv[c], 2);
  }

  // each lane finishes cols c = ks, ks+4, ks+8
  const float INV = 0.031622776601683794f;
#pragma unroll
  for (int t = 0; t < 3; ++t) {
    const int c = ks + t * 4;
    if (c < 10) {
      float mean = 0.5f * mm[c];
      float sd = 0.5f * sqrtf(vv[c]);
      uint32_t idx = (uint32_t)r * 10u + (uint32_t)c;
      float eps = eps_part(k2a, k2b, idx);
      out[(size_t)r * 10 + c] = mean + sd * (eps * INV);
    }
  }
}

extern "C" void kernel_launch(void* const* d_in, const int* in_sizes, int n_in,
                              void* d_out, int out_size, void* d_ws, size_t ws_size,
                              hipStream_t stream) {
  const float* x = (const float*)d_in[0];
  const float* W1 = (const float*)d_in[1];
  const float* W2 = (const float*)d_in[2];
  float* outp = (float*)d_out;
  u16* bp = (u16*)d_ws;                           // 819200 B
  u16* hws = (u16*)((char*)d_ws + H_OFF);         // 33.5 MB

  // k1, k2 = jax.random.split(jax.random.key(42)), partitionable threefry
  uint32_t k1a, k1b, k2a, k2b;
  threefry2x32(0u, 42u, 0u, 0u, k1a, k1b);
  threefry2x32(0u, 42u, 0u, 1u, k2a, k2b);

  pack_w1<<<256, 256, 0, stream>>>(W1, bp);
  gemm1<<<(65536 / BM) * 2, 256, 0, stream>>>(x, bp, hws, k1a, k1b);
  layer2<<<65536 / 64, 256, 0, stream>>>(hws, W2, outp, k2a, k2b);
}

// Round 8
// 160.157 us; speedup vs baseline: 5.0222x; 1.5542x over previous
//
#include <hip/hip_runtime.h>
#include <hip/hip_bf16.h>
#include <cstdint>

// Net_79139067396690: MC-dropout moment-propagation MLP.
//   h   = relu(0.5*x@W1^T + 0.5*sqrt((x^2)@(W1^2)^T) * eps1/sqrt(1000))
//   out =      0.5*h@W2^T + 0.5*sqrt((h^2)@(W2^2)^T) * eps2/sqrt(1000)
// Round 8: cut VALU work. R7 was VALU-inst-bound (VALUBusy 46%, Mfma 7.5%):
//  1) RNG: -__logf((1-u)(1+u)) [hw v_log_f32] replaces library log1pf.
//  2) staging: __float2bfloat16 casts (v_cvt_pk) replace integer-RNE twiddle
//     (reference is f32; bf16 rounding mode is our own approx choice).
//  3) layer2 on MFMA with bf16 W2 pack (cols padded to 16).
// All register state NAMED (rule #20 — r3-r5 alloca-spill lesson).

#define K_DIM 784
#define KP 800                 // K padded to multiple of 32 in the W1 pack
#define N_HID 256
#define N_OUT 10
#define BM 64                  // gemm1 rows per block
#define NSTEP 25               // KP/32
#define WSQ_OFF (N_HID * KP)   // u16 offset of squared-W1 pack
#define W2_OFF (832 * 1024)    // byte offset of W2 pack in d_ws
#define W2SQ 4096              // u16 offset of squared-W2 pack
#define H_OFF (1 << 20)        // byte offset of h in d_ws
#define BM2 128                // layer2 rows per block

using short8 = __attribute__((ext_vector_type(8))) short;
using floatx4 = __attribute__((ext_vector_type(4))) float;
typedef uint16_t u16;

// ---- Threefry-2x32 (JAX-compatible) ----
__host__ __device__ inline void threefry2x32(uint32_t k0, uint32_t k1,
                                             uint32_t x0, uint32_t x1,
                                             uint32_t& o0, uint32_t& o1) {
  uint32_t ks0 = k0, ks1 = k1, ks2 = k0 ^ k1 ^ 0x1BD11BDAu;
  x0 += ks0;
  x1 += ks1;
#define TFR(r) { x0 += x1; x1 = (x1 << (r)) | (x1 >> (32 - (r))); x1 ^= x0; }
  TFR(13) TFR(15) TFR(26) TFR(6)   x0 += ks1; x1 += ks2 + 1u;
  TFR(17) TFR(29) TFR(16) TFR(24)  x0 += ks2; x1 += ks0 + 2u;
  TFR(13) TFR(15) TFR(26) TFR(6)   x0 += ks0; x1 += ks1 + 3u;
  TFR(17) TFR(29) TFR(16) TFR(24)  x0 += ks1; x1 += ks2 + 4u;
  TFR(13) TFR(15) TFR(26) TFR(6)   x0 += ks2; x1 += ks0 + 5u;
#undef TFR
  o0 = x0;
  o1 = x1;
}

// bits -> N(0,1) ~= jax.random.normal (mantissa-uniform + Giles erfinv).
// log1p replaced by hw log on the cancellation-free product (1-u)(1+u):
// worst-case tail eps error ~0.1 -> output error ~1.3e-3, within threshold.
__device__ __forceinline__ float bits_to_normal(uint32_t bits) {
  const float lo = -0.99999994f;  // nextafterf(-1,0)
  float u01 = __uint_as_float((bits >> 9) | 0x3F800000u) - 1.0f;
  float u = fmaxf(lo, u01 * 2.0f + lo);
  float w = -__logf((1.0f - u) * (1.0f + u));
  float p;
  if (w < 5.0f) {
    w -= 2.5f;
    p = 2.81022636e-08f;
    p = fmaf(p, w, 3.43273939e-07f);
    p = fmaf(p, w, -3.5233877e-06f);
    p = fmaf(p, w, -4.39150654e-06f);
    p = fmaf(p, w, 0.00021858087f);
    p = fmaf(p, w, -0.00125372503f);
    p = fmaf(p, w, -0.00417768164f);
    p = fmaf(p, w, 0.246640727f);
    p = fmaf(p, w, 1.50140941f);
  } else {
    w = sqrtf(w) - 3.0f;
    p = -0.000200214257f;
    p = fmaf(p, w, 0.000100950558f);
    p = fmaf(p, w, 0.00134934322f);
    p = fmaf(p, w, -0.00367342844f);
    p = fmaf(p, w, 0.00573950773f);
    p = fmaf(p, w, -0.0076224613f);
    p = fmaf(p, w, 0.00943887047f);
    p = fmaf(p, w, 1.00167406f);
    p = fmaf(p, w, 2.83297682f);
  }
  return 1.41421356f * (p * u);
}

__device__ __forceinline__ float eps_part(uint32_t ka, uint32_t kb, uint32_t i) {
  uint32_t o0, o1;
  threefry2x32(ka, kb, 0u, i, o0, o1);
  return bits_to_normal(o0 ^ o1);
}

// f32 -> bf16 via hw cvt (RNE); reference is f32 so any RNE cast is fine
__device__ __forceinline__ u16 cvt_bf16(float f) {
  union { __hip_bfloat16 h; u16 u; } c;
  c.h = __float2bfloat16(f);
  return c.u;
}

__device__ __forceinline__ float bf2f(u16 b) {
  return __uint_as_float((uint32_t)b << 16);
}

// ---- pre-pack W1 -> bf16 {w, w^2}, K padded to 800 with zeros ----
__global__ __launch_bounds__(256) void pack_w1(const float* __restrict__ W1,
                                               u16* __restrict__ bp) {
  const int col = blockIdx.x;  // 0..255
  for (int k = threadIdx.x; k < KP; k += 256) {
    float w = (k < K_DIM) ? W1[col * K_DIM + k] : 0.0f;
    bp[col * KP + k] = cvt_bf16(w);
    bp[WSQ_OFF + col * KP + k] = cvt_bf16(w * w);
  }
}

// ---- pre-pack W2 -> bf16 {w, w^2}, cols padded 10->16 with zeros ----
__global__ __launch_bounds__(256) void pack_w2(const float* __restrict__ W2,
                                               u16* __restrict__ w2p) {
#pragma unroll
  for (int i = 0; i < 16; ++i) {
    int g = threadIdx.x + i * 256;  // 4096 = 16*256
    int col = g >> 8, k = g & 255;
    float w = (col < N_OUT) ? W2[col * N_HID + k] : 0.0f;
    w2p[g] = cvt_bf16(w);
    w2p[W2SQ + g] = cvt_bf16(w * w);
  }
}

// ---- GEMM1 + eps1 + relu -> h (bf16, global) ----
// Block: 256 thr = 4 waves; BM=64 rows x BN=128 cols; wave = 64 x 32.
__global__ __launch_bounds__(256, 4) void gemm1(
    const float* __restrict__ x, const u16* __restrict__ bp,
    u16* __restrict__ hws, uint32_t k1a, uint32_t k1b) {
  __shared__ u16 sA[2][2][BM * 32];  // [dbuf][x, x^2][swizzled row*32+k] 16KB

  const int tid = threadIdx.x;
  const int lane = tid & 63;
  const int l15 = lane & 15;
  const int lhal = lane >> 4;      // 0..3
  const int wn = tid >> 6;         // wave id 0..3 -> 32-col strip
  const int bid = blockIdx.x;
  const int gr0 = (bid >> 1) * BM;        // row origin
  const int bc0 = (bid & 1) * 128;        // col origin

  // staging: thread -> (row 0..63, 8-wide k chunk)
  const int srow = tid >> 2;
  const int skq = (tid & 3) * 8;
  const float* xptr = x + (size_t)(gr0 + srow) * K_DIM + skq;
  const int sidx = (srow * 32 + skq) ^ ((srow & 7) << 3);

  // B offsets (u16 units) for this wave's two 16-col fragments
  const uint32_t boff0 = (uint32_t)(bc0 + wn * 32 + 0 * 16 + l15) * KP + (uint32_t)lhal * 8;
  const uint32_t boff1 = (uint32_t)(bc0 + wn * 32 + 1 * 16 + l15) * KP + (uint32_t)lhal * 8;

  // A fragment LDS indices (rows i*16 + l15, k-group lhal*8), NAMED
#define AIDX(i) ((((i * 16 + l15) * 32 + lhal * 8)) ^ (((i * 16 + l15) & 7) << 3))
  const int aidx0 = AIDX(0);
  const int aidx1 = AIDX(1);
  const int aidx2 = AIDX(2);
  const int aidx3 = AIDX(3);
#undef AIDX

  // NAMED accumulators: am{i}{j}, av{i}{j}, i=0..3, j=0..1
#define DECL_ACC(i) \
  floatx4 am##i##0 = {0.f, 0.f, 0.f, 0.f}, am##i##1 = {0.f, 0.f, 0.f, 0.f}; \
  floatx4 av##i##0 = {0.f, 0.f, 0.f, 0.f}, av##i##1 = {0.f, 0.f, 0.f, 0.f};
  DECL_ACC(0) DECL_ACC(1) DECL_ACC(2) DECL_ACC(3)
#undef DECL_ACC

  float4 q0, q1;
  auto loadX = [&](int kk) {
    if (kk + skq + 8 <= K_DIM) {  // zero-fill the 784..799 tail
      q0 = *reinterpret_cast<const float4*>(xptr + kk);
      q1 = *reinterpret_cast<const float4*>(xptr + kk + 4);
    } else {
      q0 = make_float4(0.f, 0.f, 0.f, 0.f);
      q1 = make_float4(0.f, 0.f, 0.f, 0.f);
    }
  };
  auto writeA = [&](int buf) {
    short8 va, v2;
    va[0] = (short)cvt_bf16(q0.x); v2[0] = (short)cvt_bf16(q0.x * q0.x);
    va[1] = (short)cvt_bf16(q0.y); v2[1] = (short)cvt_bf16(q0.y * q0.y);
    va[2] = (short)cvt_bf16(q0.z); v2[2] = (short)cvt_bf16(q0.z * q0.z);
    va[3] = (short)cvt_bf16(q0.w); v2[3] = (short)cvt_bf16(q0.w * q0.w);
    va[4] = (short)cvt_bf16(q1.x); v2[4] = (short)cvt_bf16(q1.x * q1.x);
    va[5] = (short)cvt_bf16(q1.y); v2[5] = (short)cvt_bf16(q1.y * q1.y);
    va[6] = (short)cvt_bf16(q1.z); v2[6] = (short)cvt_bf16(q1.z * q1.z);
    va[7] = (short)cvt_bf16(q1.w); v2[7] = (short)cvt_bf16(q1.w * q1.w);
    *reinterpret_cast<short8*>(&sA[buf][0][sidx]) = va;
    *reinterpret_cast<short8*>(&sA[buf][1][sidx]) = v2;
  };

  loadX(0);
  writeA(0);
  __syncthreads();

  for (int s = 0; s < NSTEP; ++s) {
    const int cur = s & 1, nxt = cur ^ 1;
    const bool have = (s + 1 < NSTEP);
    const int kk = s * 32;

    const u16* bpk = bp + kk;
    const short8 bm0 = *reinterpret_cast<const short8*>(&bpk[boff0]);
    const short8 bm1 = *reinterpret_cast<const short8*>(&bpk[boff1]);
    const short8 bv0 = *reinterpret_cast<const short8*>(&bpk[WSQ_OFF + boff0]);
    const short8 bv1 = *reinterpret_cast<const short8*>(&bpk[WSQ_OFF + boff1]);

    if (have) loadX(kk + 32);

    const u16* sc0 = &sA[cur][0][0];
    const u16* sc1 = &sA[cur][1][0];
#define STEP_I(i) { \
    const short8 af = *reinterpret_cast<const short8*>(&sc0[aidx##i]); \
    const short8 ag = *reinterpret_cast<const short8*>(&sc1[aidx##i]); \
    am##i##0 = __builtin_amdgcn_mfma_f32_16x16x32_bf16(af, bm0, am##i##0, 0, 0, 0); \
    av##i##0 = __builtin_amdgcn_mfma_f32_16x16x32_bf16(ag, bv0, av##i##0, 0, 0, 0); \
    am##i##1 = __builtin_amdgcn_mfma_f32_16x16x32_bf16(af, bm1, am##i##1, 0, 0, 0); \
    av##i##1 = __builtin_amdgcn_mfma_f32_16x16x32_bf16(ag, bv1, av##i##1, 0, 0, 0); }
    STEP_I(0) STEP_I(1) STEP_I(2) STEP_I(3)
#undef STEP_I

    if (have) writeA(nxt);
    __syncthreads();
  }

  // epilogue: eps1 + relu -> h (bf16) in global ws
  const float INV = 0.031622776601683794f;  // 1/sqrt(1000)
#define EPIG(AM, AV, G, I, J) do { \
    const int rl_ = I * 16 + lhal * 4 + (G); \
    const int c_ = bc0 + wn * 32 + J * 16 + l15; \
    float mean_ = 0.5f * (AM)[G]; \
    float sd_ = 0.5f * sqrtf((AV)[G]); \
    uint32_t idx_ = (uint32_t)(gr0 + rl_) * 256u + (uint32_t)c_; \
    float eps_ = eps_part(k1a, k1b, idx_); \
    float h_ = fmaxf(mean_ + sd_ * (eps_ * INV), 0.0f); \
    hws[(size_t)(gr0 + rl_) * 256 + c_] = cvt_bf16(h_); \
  } while (0)
#define EPI(i, j) do { \
    EPIG(am##i##j, av##i##j, 0, i, j); \
    EPIG(am##i##j, av##i##j, 1, i, j); \
    EPIG(am##i##j, av##i##j, 2, i, j); \
    EPIG(am##i##j, av##i##j, 3, i, j); \
  } while (0)
  EPI(0, 0); EPI(0, 1); EPI(1, 0); EPI(1, 1);
  EPI(2, 0); EPI(2, 1); EPI(3, 0); EPI(3, 1);
#undef EPI
#undef EPIG
}

// ---- layer 2 on MFMA: out = 0.5*h@W2^T + 0.5*sqrt((h^2)@(W2^2)^T)*eps2/sqrt(Z)
// Block: 256 thr = 4 waves; BM2=128 rows; wave = 32 rows x 16 cols; K=256.
__global__ __launch_bounds__(256, 4) void layer2(
    const u16* __restrict__ hws, const u16* __restrict__ w2p,
    float* __restrict__ out, uint32_t k2a, uint32_t k2b) {
  __shared__ u16 sH[2][BM2 * 32];  // [h, h^2][swizzled row*32+k] 16KB

  const int tid = threadIdx.x;
  const int lane = tid & 63;
  const int l15 = lane & 15;
  const int lhal = lane >> 4;  // 0..3
  const int wv = tid >> 6;     // wave 0..3 -> rows wv*32..wv*32+31
  const int gr0 = blockIdx.x * BM2;

  // staging: thread -> row = tid>>1, 16-u16 half = tid&1 (64B/row coalesced)
  const int srow = tid >> 1;
  const int sq = (tid & 1) * 16;
  const u16* hrow = hws + (size_t)(gr0 + srow) * 256 + sq;
  const int sidx0 = (srow * 32 + sq) ^ ((srow & 7) << 3);
  const int sidx1 = (srow * 32 + sq + 8) ^ ((srow & 7) << 3);

  // B offsets (u16): col = l15, kgroup = lhal
  const uint32_t boff = (uint32_t)l15 * 256 + (uint32_t)lhal * 8;

  // A fragment LDS indices: rows wv*32 + i*16 + l15
#define AIDX2(i) ((((wv * 32 + i * 16 + l15) * 32 + lhal * 8)) ^ (((wv * 32 + i * 16 + l15) & 7) << 3))
  const int aidx0 = AIDX2(0);
  const int aidx1 = AIDX2(1);
#undef AIDX2

  floatx4 am0 = {0.f, 0.f, 0.f, 0.f}, am1 = {0.f, 0.f, 0.f, 0.f};
  floatx4 av0 = {0.f, 0.f, 0.f, 0.f}, av1 = {0.f, 0.f, 0.f, 0.f};

  for (int s = 0; s < 8; ++s) {
    __syncthreads();  // prev-step readers done before overwrite
    const short8 c0 = *reinterpret_cast<const short8*>(&hrow[s * 32]);
    const short8 c1 = *reinterpret_cast<const short8*>(&hrow[s * 32 + 8]);
    short8 s0, s1;
#define SQE(D, S, E) { const float f_ = bf2f((u16)(S)[E]); (D)[E] = (short)cvt_bf16(f_ * f_); }
    SQE(s0, c0, 0) SQE(s0, c0, 1) SQE(s0, c0, 2) SQE(s0, c0, 3)
    SQE(s0, c0, 4) SQE(s0, c0, 5) SQE(s0, c0, 6) SQE(s0, c0, 7)
    SQE(s1, c1, 0) SQE(s1, c1, 1) SQE(s1, c1, 2) SQE(s1, c1, 3)
    SQE(s1, c1, 4) SQE(s1, c1, 5) SQE(s1, c1, 6) SQE(s1, c1, 7)
#undef SQE
    *reinterpret_cast<short8*>(&sH[0][sidx0]) = c0;
    *reinterpret_cast<short8*>(&sH[0][sidx1]) = c1;
    *reinterpret_cast<short8*>(&sH[1][sidx0]) = s0;
    *reinterpret_cast<short8*>(&sH[1][sidx1]) = s1;
    __syncthreads();

    const short8 bm = *reinterpret_cast<const short8*>(&w2p[boff + s * 32]);
    const short8 bv = *reinterpret_cast<const short8*>(&w2p[W2SQ + boff + s * 32]);
    const short8 af0 = *reinterpret_cast<const short8*>(&sH[0][aidx0]);
    const short8 af1 = *reinterpret_cast<const short8*>(&sH[0][aidx1]);
    const short8 ag0 = *reinterpret_cast<const short8*>(&sH[1][aidx0]);
    const short8 ag1 = *reinterpret_cast<const short8*>(&sH[1][aidx1]);
    am0 = __builtin_amdgcn_mfma_f32_16x16x32_bf16(af0, bm, am0, 0, 0, 0);
    av0 = __builtin_amdgcn_mfma_f32_16x16x32_bf16(ag0, bv, av0, 0, 0, 0);
    am1 = __builtin_amdgcn_mfma_f32_16x16x32_bf16(af1, bm, am1, 0, 0, 0);
    av1 = __builtin_amdgcn_mfma_f32_16x16x32_bf16(ag1, bv, av1, 0, 0, 0);
  }

  // epilogue: C/D layout col=l15, row=(lane>>4)*4+g; only cols 0..9 exist
  const float INV = 0.031622776601683794f;
  if (l15 < N_OUT) {
#define L2E(I, G) do { \
    const int row_ = gr0 + wv * 32 + I * 16 + lhal * 4 + (G); \
    float mean_ = 0.5f * am##I[G]; \
    float sd_ = 0.5f * sqrtf(av##I[G]); \
    float eps_ = eps_part(k2a, k2b, (uint32_t)row_ * 10u + (uint32_t)l15); \
    out[(size_t)row_ * 10 + l15] = mean_ + sd_ * (eps_ * INV); \
  } while (0)
    L2E(0, 0); L2E(0, 1); L2E(0, 2); L2E(0, 3);
    L2E(1, 0); L2E(1, 1); L2E(1, 2); L2E(1, 3);
#undef L2E
  }
}

extern "C" void kernel_launch(void* const* d_in, const int* in_sizes, int n_in,
                              void* d_out, int out_size, void* d_ws, size_t ws_size,
                              hipStream_t stream) {
  const float* x = (const float*)d_in[0];
  const float* W1 = (const float*)d_in[1];
  const float* W2 = (const float*)d_in[2];
  float* outp = (float*)d_out;
  u16* bp = (u16*)d_ws;                           // 819200 B
  u16* w2p = (u16*)((char*)d_ws + W2_OFF);        // 16 KB
  u16* hws = (u16*)((char*)d_ws + H_OFF);         // 33.5 MB

  // k1, k2 = jax.random.split(jax.random.key(42)), partitionable threefry
  uint32_t k1a, k1b, k2a, k2b;
  threefry2x32(0u, 42u, 0u, 0u, k1a, k1b);
  threefry2x32(0u, 42u, 0u, 1u, k2a, k2b);

  pack_w1<<<256, 256, 0, stream>>>(W1, bp);
  pack_w2<<<1, 256, 0, stream>>>(W2, w2p);
  gemm1<<<(65536 / BM) * 2, 256, 0, stream>>>(x, bp, hws, k1a, k1b);
  layer2<<<65536 / BM2, 256, 0, stream>>>(hws, w2p, outp, k2a, k2b);
}

// Round 9
// 158.777 us; speedup vs baseline: 5.0659x; 1.0087x over previous
//
#include <hip/hip_runtime.h>
#include <hip/hip_bf16.h>
#include <cstdint>

// Net_79139067396690: MC-dropout moment-propagation MLP.
//   h   = relu(0.5*x@W1^T + 0.5*sqrt((x^2)@(W1^2)^T) * eps1/sqrt(1000))
//   out =      0.5*h@W2^T + 0.5*sqrt((h^2)@(W2^2)^T) * eps2/sqrt(1000)
// Round 9: R8 still latency-bound (Mfma 9%, VALU 33%, HBM 13% — all idle).
// Root cause: no B prefetch (removed in r4 vs the alloca spill) -> every
// K-step stalls ~300cyc on L2 loads feeding the first MFMA. Fix: NAMED
// ping/pong B register sets (rule #20 safe), 2-step-unrolled K-loop.
// Reg budget: ~96+16 unified < 128 @ 4 waves/SIMD -> no spill expected.

#define K_DIM 784
#define KP 800                 // K padded to multiple of 32 in the W1 pack
#define N_HID 256
#define N_OUT 10
#define BM 64                  // gemm1 rows per block
#define NSTEP 25               // KP/32
#define WSQ_OFF (N_HID * KP)   // u16 offset of squared-W1 pack
#define W2_OFF (832 * 1024)    // byte offset of W2 pack in d_ws
#define W2SQ 4096              // u16 offset of squared-W2 pack
#define H_OFF (1 << 20)        // byte offset of h in d_ws
#define BM2 128                // layer2 rows per block

using short8 = __attribute__((ext_vector_type(8))) short;
using floatx4 = __attribute__((ext_vector_type(4))) float;
typedef uint16_t u16;

// ---- Threefry-2x32 (JAX-compatible) ----
__host__ __device__ inline void threefry2x32(uint32_t k0, uint32_t k1,
                                             uint32_t x0, uint32_t x1,
                                             uint32_t& o0, uint32_t& o1) {
  uint32_t ks0 = k0, ks1 = k1, ks2 = k0 ^ k1 ^ 0x1BD11BDAu;
  x0 += ks0;
  x1 += ks1;
#define TFR(r) { x0 += x1; x1 = (x1 << (r)) | (x1 >> (32 - (r))); x1 ^= x0; }
  TFR(13) TFR(15) TFR(26) TFR(6)   x0 += ks1; x1 += ks2 + 1u;
  TFR(17) TFR(29) TFR(16) TFR(24)  x0 += ks2; x1 += ks0 + 2u;
  TFR(13) TFR(15) TFR(26) TFR(6)   x0 += ks0; x1 += ks1 + 3u;
  TFR(17) TFR(29) TFR(16) TFR(24)  x0 += ks1; x1 += ks2 + 4u;
  TFR(13) TFR(15) TFR(26) TFR(6)   x0 += ks2; x1 += ks0 + 5u;
#undef TFR
  o0 = x0;
  o1 = x1;
}

// bits -> N(0,1) ~= jax.random.normal (mantissa-uniform + Giles erfinv).
// log1p replaced by hw log on the cancellation-free product (1-u)(1+u).
__device__ __forceinline__ float bits_to_normal(uint32_t bits) {
  const float lo = -0.99999994f;  // nextafterf(-1,0)
  float u01 = __uint_as_float((bits >> 9) | 0x3F800000u) - 1.0f;
  float u = fmaxf(lo, u01 * 2.0f + lo);
  float w = -__logf((1.0f - u) * (1.0f + u));
  float p;
  if (w < 5.0f) {
    w -= 2.5f;
    p = 2.81022636e-08f;
    p = fmaf(p, w, 3.43273939e-07f);
    p = fmaf(p, w, -3.5233877e-06f);
    p = fmaf(p, w, -4.39150654e-06f);
    p = fmaf(p, w, 0.00021858087f);
    p = fmaf(p, w, -0.00125372503f);
    p = fmaf(p, w, -0.00417768164f);
    p = fmaf(p, w, 0.246640727f);
    p = fmaf(p, w, 1.50140941f);
  } else {
    w = sqrtf(w) - 3.0f;
    p = -0.000200214257f;
    p = fmaf(p, w, 0.000100950558f);
    p = fmaf(p, w, 0.00134934322f);
    p = fmaf(p, w, -0.00367342844f);
    p = fmaf(p, w, 0.00573950773f);
    p = fmaf(p, w, -0.0076224613f);
    p = fmaf(p, w, 0.00943887047f);
    p = fmaf(p, w, 1.00167406f);
    p = fmaf(p, w, 2.83297682f);
  }
  return 1.41421356f * (p * u);
}

__device__ __forceinline__ float eps_part(uint32_t ka, uint32_t kb, uint32_t i) {
  uint32_t o0, o1;
  threefry2x32(ka, kb, 0u, i, o0, o1);
  return bits_to_normal(o0 ^ o1);
}

// f32 -> bf16 via hw cvt (RNE)
__device__ __forceinline__ u16 cvt_bf16(float f) {
  union { __hip_bfloat16 h; u16 u; } c;
  c.h = __float2bfloat16(f);
  return c.u;
}

__device__ __forceinline__ float bf2f(u16 b) {
  return __uint_as_float((uint32_t)b << 16);
}

// ---- pre-pack W1 -> bf16 {w, w^2}, K padded to 800 with zeros ----
__global__ __launch_bounds__(256) void pack_w1(const float* __restrict__ W1,
                                               u16* __restrict__ bp) {
  const int col = blockIdx.x;  // 0..255
  for (int k = threadIdx.x; k < KP; k += 256) {
    float w = (k < K_DIM) ? W1[col * K_DIM + k] : 0.0f;
    bp[col * KP + k] = cvt_bf16(w);
    bp[WSQ_OFF + col * KP + k] = cvt_bf16(w * w);
  }
}

// ---- pre-pack W2 -> bf16 {w, w^2}, cols padded 10->16 with zeros ----
__global__ __launch_bounds__(256) void pack_w2(const float* __restrict__ W2,
                                               u16* __restrict__ w2p) {
#pragma unroll
  for (int i = 0; i < 16; ++i) {
    int g = threadIdx.x + i * 256;  // 4096 = 16*256
    int col = g >> 8, k = g & 255;
    float w = (col < N_OUT) ? W2[col * N_HID + k] : 0.0f;
    w2p[g] = cvt_bf16(w);
    w2p[W2SQ + g] = cvt_bf16(w * w);
  }
}

// ---- GEMM1 + eps1 + relu -> h (bf16, global) ----
// Block: 256 thr = 4 waves; BM=64 rows x BN=128 cols; wave = 64 x 32.
__global__ __launch_bounds__(256, 4) void gemm1(
    const float* __restrict__ x, const u16* __restrict__ bp,
    u16* __restrict__ hws, uint32_t k1a, uint32_t k1b) {
  __shared__ u16 sA[2][2][BM * 32];  // [dbuf][x, x^2][swizzled row*32+k] 16KB

  const int tid = threadIdx.x;
  const int lane = tid & 63;
  const int l15 = lane & 15;
  const int lhal = lane >> 4;      // 0..3
  const int wn = tid >> 6;         // wave id 0..3 -> 32-col strip
  const int bid = blockIdx.x;
  const int gr0 = (bid >> 1) * BM;        // row origin
  const int bc0 = (bid & 1) * 128;        // col origin

  // staging: thread -> (row 0..63, 8-wide k chunk)
  const int srow = tid >> 2;
  const int skq = (tid & 3) * 8;
  const float* xptr = x + (size_t)(gr0 + srow) * K_DIM + skq;
  const int sidx = (srow * 32 + skq) ^ ((srow & 7) << 3);

  // B offsets (u16 units) for this wave's two 16-col fragments
  const uint32_t boff0 = (uint32_t)(bc0 + wn * 32 + 0 * 16 + l15) * KP + (uint32_t)lhal * 8;
  const uint32_t boff1 = (uint32_t)(bc0 + wn * 32 + 1 * 16 + l15) * KP + (uint32_t)lhal * 8;

  // A fragment LDS indices (rows i*16 + l15, k-group lhal*8), NAMED
#define AIDX(i) ((((i * 16 + l15) * 32 + lhal * 8)) ^ (((i * 16 + l15) & 7) << 3))
  const int aidx0 = AIDX(0);
  const int aidx1 = AIDX(1);
  const int aidx2 = AIDX(2);
  const int aidx3 = AIDX(3);
#undef AIDX

  // NAMED accumulators: am{i}{j}, av{i}{j}, i=0..3, j=0..1
#define DECL_ACC(i) \
  floatx4 am##i##0 = {0.f, 0.f, 0.f, 0.f}, am##i##1 = {0.f, 0.f, 0.f, 0.f}; \
  floatx4 av##i##0 = {0.f, 0.f, 0.f, 0.f}, av##i##1 = {0.f, 0.f, 0.f, 0.f};
  DECL_ACC(0) DECL_ACC(1) DECL_ACC(2) DECL_ACC(3)
#undef DECL_ACC

  // NAMED ping/pong B register sets (16 VGPR each)
  short8 bm0P, bm1P, bv0P, bv1P;
  short8 bm0Q, bm1Q, bv0Q, bv1Q;
#define LOADB(S, KK) do { \
    const u16* bpk_ = bp + (KK); \
    bm0##S = *reinterpret_cast<const short8*>(&bpk_[boff0]); \
    bm1##S = *reinterpret_cast<const short8*>(&bpk_[boff1]); \
    bv0##S = *reinterpret_cast<const short8*>(&bpk_[WSQ_OFF + boff0]); \
    bv1##S = *reinterpret_cast<const short8*>(&bpk_[WSQ_OFF + boff1]); \
  } while (0)

  float4 q0, q1;
  auto loadX = [&](int kk) {
    if (kk + skq + 8 <= K_DIM) {  // zero-fill the 784..799 tail
      q0 = *reinterpret_cast<const float4*>(xptr + kk);
      q1 = *reinterpret_cast<const float4*>(xptr + kk + 4);
    } else {
      q0 = make_float4(0.f, 0.f, 0.f, 0.f);
      q1 = make_float4(0.f, 0.f, 0.f, 0.f);
    }
  };
  auto writeA = [&](int buf) {
    short8 va, v2;
    va[0] = (short)cvt_bf16(q0.x); v2[0] = (short)cvt_bf16(q0.x * q0.x);
    va[1] = (short)cvt_bf16(q0.y); v2[1] = (short)cvt_bf16(q0.y * q0.y);
    va[2] = (short)cvt_bf16(q0.z); v2[2] = (short)cvt_bf16(q0.z * q0.z);
    va[3] = (short)cvt_bf16(q0.w); v2[3] = (short)cvt_bf16(q0.w * q0.w);
    va[4] = (short)cvt_bf16(q1.x); v2[4] = (short)cvt_bf16(q1.x * q1.x);
    va[5] = (short)cvt_bf16(q1.y); v2[5] = (short)cvt_bf16(q1.y * q1.y);
    va[6] = (short)cvt_bf16(q1.z); v2[6] = (short)cvt_bf16(q1.z * q1.z);
    va[7] = (short)cvt_bf16(q1.w); v2[7] = (short)cvt_bf16(q1.w * q1.w);
    *reinterpret_cast<short8*>(&sA[buf][0][sidx]) = va;
    *reinterpret_cast<short8*>(&sA[buf][1][sidx]) = v2;
  };

  // One K-step: uses B set CUR (already resident), prefetches set NXT.
#define KSTEP(S_, CUR, NXT, LAST) do { \
    const int kk_ = (S_) * 32; \
    if (!(LAST)) { loadX(kk_ + 32); LOADB(NXT, kk_ + 32); } \
    const u16* sc0_ = &sA[(S_) & 1][0][0]; \
    const u16* sc1_ = &sA[(S_) & 1][1][0]; \
    { \
      const short8 af0_ = *reinterpret_cast<const short8*>(&sc0_[aidx0]); \
      const short8 ag0_ = *reinterpret_cast<const short8*>(&sc1_[aidx0]); \
      const short8 af1_ = *reinterpret_cast<const short8*>(&sc0_[aidx1]); \
      const short8 ag1_ = *reinterpret_cast<const short8*>(&sc1_[aidx1]); \
      const short8 af2_ = *reinterpret_cast<const short8*>(&sc0_[aidx2]); \
      const short8 ag2_ = *reinterpret_cast<const short8*>(&sc1_[aidx2]); \
      const short8 af3_ = *reinterpret_cast<const short8*>(&sc0_[aidx3]); \
      const short8 ag3_ = *reinterpret_cast<const short8*>(&sc1_[aidx3]); \
      am00 = __builtin_amdgcn_mfma_f32_16x16x32_bf16(af0_, bm0##CUR, am00, 0, 0, 0); \
      av00 = __builtin_amdgcn_mfma_f32_16x16x32_bf16(ag0_, bv0##CUR, av00, 0, 0, 0); \
      am01 = __builtin_amdgcn_mfma_f32_16x16x32_bf16(af0_, bm1##CUR, am01, 0, 0, 0); \
      av01 = __builtin_amdgcn_mfma_f32_16x16x32_bf16(ag0_, bv1##CUR, av01, 0, 0, 0); \
      am10 = __builtin_amdgcn_mfma_f32_16x16x32_bf16(af1_, bm0##CUR, am10, 0, 0, 0); \
      av10 = __builtin_amdgcn_mfma_f32_16x16x32_bf16(ag1_, bv0##CUR, av10, 0, 0, 0); \
      am11 = __builtin_amdgcn_mfma_f32_16x16x32_bf16(af1_, bm1##CUR, am11, 0, 0, 0); \
      av11 = __builtin_amdgcn_mfma_f32_16x16x32_bf16(ag1_, bv1##CUR, av11, 0, 0, 0); \
      am20 = __builtin_amdgcn_mfma_f32_16x16x32_bf16(af2_, bm0##CUR, am20, 0, 0, 0); \
      av20 = __builtin_amdgcn_mfma_f32_16x16x32_bf16(ag2_, bv0##CUR, av20, 0, 0, 0); \
      am21 = __builtin_amdgcn_mfma_f32_16x16x32_bf16(af2_, bm1##CUR, am21, 0, 0, 0); \
      av21 = __builtin_amdgcn_mfma_f32_16x16x32_bf16(ag2_, bv1##CUR, av21, 0, 0, 0); \
      am30 = __builtin_amdgcn_mfma_f32_16x16x32_bf16(af3_, bm0##CUR, am30, 0, 0, 0); \
      av30 = __builtin_amdgcn_mfma_f32_16x16x32_bf16(ag3_, bv0##CUR, av30, 0, 0, 0); \
      am31 = __builtin_amdgcn_mfma_f32_16x16x32_bf16(af3_, bm1##CUR, am31, 0, 0, 0); \
      av31 = __builtin_amdgcn_mfma_f32_16x16x32_bf16(ag3_, bv1##CUR, av31, 0, 0, 0); \
    } \
    if (!(LAST)) writeA(((S_) & 1) ^ 1); \
    __syncthreads(); \
  } while (0)

  // prologue: stage step 0 (A tile + B regs)
  loadX(0);
  writeA(0);
  LOADB(P, 0);
  __syncthreads();

  for (int s = 0; s < 24; s += 2) {
    KSTEP(s, P, Q, false);
    KSTEP(s + 1, Q, P, false);
  }
  KSTEP(24, P, Q, true);
#undef KSTEP
#undef LOADB

  // epilogue: eps1 + relu -> h (bf16) in global ws
  const float INV = 0.031622776601683794f;  // 1/sqrt(1000)
#define EPIG(AM, AV, G, I, J) do { \
    const int rl_ = I * 16 + lhal * 4 + (G); \
    const int c_ = bc0 + wn * 32 + J * 16 + l15; \
    float mean_ = 0.5f * (AM)[G]; \
    float sd_ = 0.5f * sqrtf((AV)[G]); \
    uint32_t idx_ = (uint32_t)(gr0 + rl_) * 256u + (uint32_t)c_; \
    float eps_ = eps_part(k1a, k1b, idx_); \
    float h_ = fmaxf(mean_ + sd_ * (eps_ * INV), 0.0f); \
    hws[(size_t)(gr0 + rl_) * 256 + c_] = cvt_bf16(h_); \
  } while (0)
#define EPI(i, j) do { \
    EPIG(am##i##j, av##i##j, 0, i, j); \
    EPIG(am##i##j, av##i##j, 1, i, j); \
    EPIG(am##i##j, av##i##j, 2, i, j); \
    EPIG(am##i##j, av##i##j, 3, i, j); \
  } while (0)
  EPI(0, 0); EPI(0, 1); EPI(1, 0); EPI(1, 1);
  EPI(2, 0); EPI(2, 1); EPI(3, 0); EPI(3, 1);
#undef EPI
#undef EPIG
}

// ---- layer 2 on MFMA: out = 0.5*h@W2^T + 0.5*sqrt((h^2)@(W2^2)^T)*eps2/sqrt(Z)
// Block: 256 thr = 4 waves; BM2=128 rows; wave = 32 rows x 16 cols; K=256.
__global__ __launch_bounds__(256, 4) void layer2(
    const u16* __restrict__ hws, const u16* __restrict__ w2p,
    float* __restrict__ out, uint32_t k2a, uint32_t k2b) {
  __shared__ u16 sH[2][BM2 * 32];  // [h, h^2][swizzled row*32+k] 16KB

  const int tid = threadIdx.x;
  const int lane = tid & 63;
  const int l15 = lane & 15;
  const int lhal = lane >> 4;  // 0..3
  const int wv = tid >> 6;     // wave 0..3 -> rows wv*32..wv*32+31
  const int gr0 = blockIdx.x * BM2;

  // staging: thread -> row = tid>>1, 16-u16 half = tid&1 (64B/row coalesced)
  const int srow = tid >> 1;
  const int sq = (tid & 1) * 16;
  const u16* hrow = hws + (size_t)(gr0 + srow) * 256 + sq;
  const int sidx0 = (srow * 32 + sq) ^ ((srow & 7) << 3);
  const int sidx1 = (srow * 32 + sq + 8) ^ ((srow & 7) << 3);

  // B offsets (u16): col = l15, kgroup = lhal
  const uint32_t boff = (uint32_t)l15 * 256 + (uint32_t)lhal * 8;

  // A fragment LDS indices: rows wv*32 + i*16 + l15
#define AIDX2(i) ((((wv * 32 + i * 16 + l15) * 32 + lhal * 8)) ^ (((wv * 32 + i * 16 + l15) & 7) << 3))
  const int aidx0 = AIDX2(0);
  const int aidx1 = AIDX2(1);
#undef AIDX2

  floatx4 am0 = {0.f, 0.f, 0.f, 0.f}, am1 = {0.f, 0.f, 0.f, 0.f};
  floatx4 av0 = {0.f, 0.f, 0.f, 0.f}, av1 = {0.f, 0.f, 0.f, 0.f};

  for (int s = 0; s < 8; ++s) {
    __syncthreads();  // prev-step readers done before overwrite
    const short8 c0 = *reinterpret_cast<const short8*>(&hrow[s * 32]);
    const short8 c1 = *reinterpret_cast<const short8*>(&hrow[s * 32 + 8]);
    short8 s0, s1;
#define SQE(D, S, E) { const float f_ = bf2f((u16)(S)[E]); (D)[E] = (short)cvt_bf16(f_ * f_); }
    SQE(s0, c0, 0) SQE(s0, c0, 1) SQE(s0, c0, 2) SQE(s0, c0, 3)
    SQE(s0, c0, 4) SQE(s0, c0, 5) SQE(s0, c0, 6) SQE(s0, c0, 7)
    SQE(s1, c1, 0) SQE(s1, c1, 1) SQE(s1, c1, 2) SQE(s1, c1, 3)
    SQE(s1, c1, 4) SQE(s1, c1, 5) SQE(s1, c1, 6) SQE(s1, c1, 7)
#undef SQE
    *reinterpret_cast<short8*>(&sH[0][sidx0]) = c0;
    *reinterpret_cast<short8*>(&sH[0][sidx1]) = c1;
    *reinterpret_cast<short8*>(&sH[1][sidx0]) = s0;
    *reinterpret_cast<short8*>(&sH[1][sidx1]) = s1;
    __syncthreads();

    const short8 bm = *reinterpret_cast<const short8*>(&w2p[boff + s * 32]);
    const short8 bv = *reinterpret_cast<const short8*>(&w2p[W2SQ + boff + s * 32]);
    const short8 af0 = *reinterpret_cast<const short8*>(&sH[0][aidx0]);
    const short8 af1 = *reinterpret_cast<const short8*>(&sH[0][aidx1]);
    const short8 ag0 = *reinterpret_cast<const short8*>(&sH[1][aidx0]);
    const short8 ag1 = *reinterpret_cast<const short8*>(&sH[1][aidx1]);
    am0 = __builtin_amdgcn_mfma_f32_16x16x32_bf16(af0, bm, am0, 0, 0, 0);
    av0 = __builtin_amdgcn_mfma_f32_16x16x32_bf16(ag0, bv, av0, 0, 0, 0);
    am1 = __builtin_amdgcn_mfma_f32_16x16x32_bf16(af1, bm, am1, 0, 0, 0);
    av1 = __builtin_amdgcn_mfma_f32_16x16x32_bf16(ag1, bv, av1, 0, 0, 0);
  }

  // epilogue: C/D layout col=l15, row=(lane>>4)*4+g; only cols 0..9 exist
  const float INV = 0.031622776601683794f;
  if (l15 < N_OUT) {
#define L2E(I, G) do { \
    const int row_ = gr0 + wv * 32 + I * 16 + lhal * 4 + (G); \
    float mean_ = 0.5f * am##I[G]; \
    float sd_ = 0.5f * sqrtf(av##I[G]); \
    float eps_ = eps_part(k2a, k2b, (uint32_t)row_ * 10u + (uint32_t)l15); \
    out[(size_t)row_ * 10 + l15] = mean_ + sd_ * (eps_ * INV); \
  } while (0)
    L2E(0, 0); L2E(0, 1); L2E(0, 2); L2E(0, 3);
    L2E(1, 0); L2E(1, 1); L2E(1, 2); L2E(1, 3);
#undef L2E
  }
}

extern "C" void kernel_launch(void* const* d_in, const int* in_sizes, int n_in,
                              void* d_out, int out_size, void* d_ws, size_t ws_size,
                              hipStream_t stream) {
  const float* x = (const float*)d_in[0];
  const float* W1 = (const float*)d_in[1];
  const float* W2 = (const float*)d_in[2];
  float* outp = (float*)d_out;
  u16* bp = (u16*)d_ws;                           // 819200 B
  u16* w2p = (u16*)((char*)d_ws + W2_OFF);        // 16 KB
  u16* hws = (u16*)((char*)d_ws + H_OFF);         // 33.5 MB

  // k1, k2 = jax.random.split(jax.random.key(42)), partitionable threefry
  uint32_t k1a, k1b, k2a, k2b;
  threefry2x32(0u, 42u, 0u, 0u, k1a, k1b);
  threefry2x32(0u, 42u, 0u, 1u, k2a, k2b);

  pack_w1<<<256, 256, 0, stream>>>(W1, bp);
  pack_w2<<<1, 256, 0, stream>>>(W2, w2p);
  gemm1<<<(65536 / BM) * 2, 256, 0, stream>>>(x, bp, hws, k1a, k1b);
  layer2<<<65536 / BM2, 256, 0, stream>>>(hws, w2p, outp, k2a, k2b);
}